// Round 8
// baseline (203.716 us; speedup 1.0000x reference)
//
#include <hip/hip_runtime.h>
#include <hip/hip_bf16.h>
#include <math.h>

typedef __bf16 bf16;
typedef __bf16 bf16x4 __attribute__((ext_vector_type(4)));
typedef __bf16 bf16x8 __attribute__((ext_vector_type(8)));
typedef float f32x4 __attribute__((ext_vector_type(4)));

#define SEQ  2048
#define EMB  1024
#define NH   16
#define HD   64
#define MTOT 4096  // B*S

__device__ __forceinline__ void gl_lds16(const void* g, void* l) {
  __builtin_amdgcn_global_load_lds(
      (const __attribute__((address_space(1))) void*)g,
      (__attribute__((address_space(3))) void*)l, 16, 0, 0);
}

__device__ __forceinline__ f32x4 mfma16(bf16x8 a, bf16x8 b, f32x4 c) {
  return __builtin_amdgcn_mfma_f32_16x16x32_bf16(a, b, c, 0, 0, 0);
}

// log2(10000)/32
#define ROPE_C 0.41524101186092026f
// log2(e)/8 — QK scale, pre-folded into q at the projection epilogue
#define QSCL  0.1803368801111244f

// RoPE cos/sin table: tab[s*32 + j] = {cos(s*10000^(-j/32)), sin(...)}.
// 2048 x 32 float2 = 512 KB, L2-resident; replaces 64 __sincosf per thread
// in the gemm epilogue with coalesced 8B loads.
__global__ __launch_bounds__(256) void rope_tab_kernel(float2* __restrict__ tab) {
  int idx = blockIdx.x * 256 + threadIdx.x;   // 65536
  int s = idx >> 5, j = idx & 31;
  float invf = exp2f(-(float)j * ROPE_C);
  float th = (float)s * invf;
  float sn, cs;
  __sincosf(th, &sn, &cs);
  tab[idx] = make_float2(cs, sn);
}

// f32 -> bf16: 8 uniform WN-sized slices; y 0..3 = x chunks, y 4..7 = Wq..Wo.
__global__ __launch_bounds__(256) void cvt_all_kernel(
    const float* __restrict__ x,
    const float* __restrict__ w0, const float* __restrict__ w1,
    const float* __restrict__ w2, const float* __restrict__ w3,
    bf16* __restrict__ dst) {
  const int y = blockIdx.y;
  const size_t WN = (size_t)EMB * EMB;
  const float* src = (y < 4) ? (x + (size_t)y * WN)
                   : (y == 4) ? w0 : (y == 5) ? w1 : (y == 6) ? w2 : w3;
  size_t i = ((size_t)blockIdx.x * 256 + threadIdx.x) * 8;
  float4 a = *(const float4*)(src + i);
  float4 b = *(const float4*)(src + i + 4);
  bf16x8 o;
  o[0] = (bf16)a.x; o[1] = (bf16)a.y; o[2] = (bf16)a.z; o[3] = (bf16)a.w;
  o[4] = (bf16)b.x; o[5] = (bf16)b.y; o[6] = (bf16)b.z; o[7] = (bf16)b.w;
  *(bf16x8*)(dst + (size_t)y * WN + i) = o;
}

// QKV projection (unfused z, 128x128 tile, BK=64): z = blockIdx.z selects
// {q,k,v}. Swizzle (both-sides, rule 21): LDS slot p of row r holds chunk
// p^(r&7); read uses chunk (kk*4+quad)^(ml&7). RoPE on q,k via the global
// cos/sin table (no sincos in the epilogue); q pre-scaled by QSCL.
// q,k -> [bh][s][d]; v -> [bh][d][s] with each 32-s block PERMUTED for
// flash's single-b128 PV fragment.
__global__ __launch_bounds__(256) void gemm_kernel(
    const bf16* __restrict__ X,
    const bf16* __restrict__ W0, const bf16* __restrict__ W1, const bf16* __restrict__ W2,
    const float* __restrict__ B0, const float* __restrict__ B1, const float* __restrict__ B2,
    const float2* __restrict__ tab,
    bf16* __restrict__ Oq, bf16* __restrict__ Ok, bf16* __restrict__ Ovt)
{
  const int K = EMB;
  const int tid  = threadIdx.x;
  const int lane = tid & 63;
  const int w    = tid >> 6;       // wave 0..3
  const int wm   = w >> 1, wn = w & 1;
  // XCD swizzle within each z-slice: 32-block chunks per XCD.
  const int lin = blockIdx.x + blockIdx.y * 8;
  const int sw  = (lin & 7) * 32 + (lin >> 3);
  const int tile_n = (sw & 7) * 128;
  const int tile_m = (sw >> 3) * 128;
  const int z = blockIdx.z;
  const bf16*  Wsel = (z == 0) ? W0 : (z == 1 ? W1 : W2);
  const float* Bsel = (z == 0) ? B0 : (z == 1 ? B1 : B2);

  __shared__ __align__(16) unsigned char smem[33792];  // staging 32KB | CS 33792
  bf16* As = (bf16*)smem;            // 128 x 64 = 16 KB
  bf16* Bs = (bf16*)(smem + 16384);  // 128 x 64 = 16 KB

  f32x4 acc[4][4];
#pragma unroll
  for (int i = 0; i < 4; i++)
#pragma unroll
    for (int j = 0; j < 4; j++) acc[i][j] = f32x4{0.f, 0.f, 0.f, 0.f};

  const int quad  = lane >> 4;
  const int l15   = lane & 15;
  const int srow8 = lane >> 3;   // row within an 8-row staging issue
  const int p8    = lane & 7;    // 16B-chunk slot within the 128B row
  const int csrc  = p8 ^ srow8;  // global chunk feeding this LDS slot

  for (int k0 = 0; k0 < K; k0 += 64) {
#pragma unroll
    for (int i = 0; i < 4; i++) {
      const int ii = w * 4 + i;            // 8-row group 0..15
      const int r  = ii * 8 + srow8;       // tile-local row 0..127
      gl_lds16(X    + (size_t)(tile_m + r) * K + k0 + csrc * 8, As + ii * 512);
      gl_lds16(Wsel + (size_t)(tile_n + r) * K + k0 + csrc * 8, Bs + ii * 512);
    }
    __syncthreads();

#pragma unroll
    for (int kk = 0; kk < 2; kk++) {
      bf16x8 af[4], bfr[4];
#pragma unroll
      for (int mt = 0; mt < 4; mt++) {
        int ml = wm * 64 + mt * 16 + l15;
        af[mt] = *(const bf16x8*)(As + ml * 64 + (((kk * 4 + quad) ^ (ml & 7)) & 7) * 8);
      }
#pragma unroll
      for (int nt = 0; nt < 4; nt++) {
        int nl = wn * 64 + nt * 16 + l15;
        bfr[nt] = *(const bf16x8*)(Bs + nl * 64 + (((kk * 4 + quad) ^ (nl & 7)) & 7) * 8);
      }
#pragma unroll
      for (int mt = 0; mt < 4; mt++)
#pragma unroll
        for (int nt = 0; nt < 4; nt++)
          acc[mt][nt] = mfma16(af[mt], bfr[nt], acc[mt][nt]);
    }
    __syncthreads();
  }

  // ---- epilogue ----
  bf16* CS = (bf16*)smem;  // 128 rows x 132 stride
  const int b = tile_m >> 11;
  const int s0 = tile_m & (SEQ - 1);

  if (z < 2) {
    // bias + RoPE in registers (cos/sin from table), stage CS[m][n]
#pragma unroll
    for (int nt = 0; nt < 4; nt++) {
      const int nl = wn * 64 + nt * 16 + l15;
      const int n = tile_n + nl;
      const float bias = Bsel[n];
      const int j = n & 31;
#pragma unroll
      for (int mt = 0; mt < 4; mt++) {
#pragma unroll
        for (int r = 0; r < 4; r++) {
          const int ml = wm * 64 + mt * 16 + quad * 4 + r;
          float a = acc[mt][nt][r] + bias;
          float p = __shfl_xor(a, 1, 64);  // partner at d^1 (incl. its bias)
          const float2 t = tab[((s0 + ml) << 5) + j];
          float res = (n & 1) ? fmaf(p, t.y, a * t.x) : fmaf(-p, t.y, a * t.x);
          if (z == 0) res *= QSCL;  // fold QK scale+log2e into q
          CS[ml * 132 + nl] = (bf16)res;
        }
      }
    }
    __syncthreads();
    // coalesced store: 256 rows (2 heads x 128 s), 128 B each
    bf16* Odst = (z == 0) ? Oq : Ok;
#pragma unroll
    for (int g = 0; g < 8; g++) {
      int unit = g * 256 + tid;
      int chunk = unit & 7;          // 16B chunk within row
      int row = unit >> 3;           // 0..255
      int hl = row >> 7, sl = row & 127;
      bf16x8 v = *(const bf16x8*)(CS + sl * 132 + hl * 64 + chunk * 8);
      int hg = (tile_n >> 6) + hl;
      size_t o = ((size_t)(b * NH + hg) * SEQ + s0 + sl) * HD + chunk * 8;
      *(bf16x8*)(Odst + o) = v;
    }
  } else {
    // V^T: stage CS[n][perm(m)] — permute s within each 32-block so flash's
    // per-lane fragment (k = hf*16 + quad*4 + e -> pos quad*8 + hf*4 + e) is
    // contiguous 16B.
#pragma unroll
    for (int nt = 0; nt < 4; nt++) {
      const int nl = wn * 64 + nt * 16 + l15;
      const float bias = Bsel[tile_n + nl];
#pragma unroll
      for (int mt = 0; mt < 4; mt++) {
        const int mb = wm * 64 + mt * 16 + quad * 4;
#pragma unroll
        for (int r = 0; r < 4; r++) {
          const int ml = mb + r;
          const int mp = (ml & ~31) | ((ml & 12) << 1) | ((ml & 16) >> 2) | (ml & 3);
          CS[nl * 132 + mp] = (bf16)(acc[mt][nt][r] + bias);
        }
      }
    }
    __syncthreads();
    // coalesced store: 128 rows (d), 256 B each
#pragma unroll
    for (int g = 0; g < 8; g++) {
      int unit = g * 256 + tid;
      int chunk = unit & 15;         // 16B chunk within row
      int row = unit >> 4;           // 0..127 (n_local)
      bf16x8 v = *(const bf16x8*)(CS + row * 132 + chunk * 8);
      int nglob = tile_n + row;
      int d = nglob & 63, hg = nglob >> 6;
      size_t o = ((size_t)(b * NH + hg) * HD + d) * SEQ + s0 + chunk * 8;
      *(bf16x8*)(Ovt + o) = v;
    }
  }
}

// Out projection: 64x128 tiles, BK=64, 512 blocks. XCD-swizzled.
__global__ __launch_bounds__(256) void gemm_o_kernel(
    const bf16* __restrict__ X,     // attn out [4096][1024] bf16
    const bf16* __restrict__ W,     // Wo [1024][1024] bf16
    const float* __restrict__ Bb,   // bo
    float* __restrict__ Out)        // [4096][1024] f32
{
  const int tid = threadIdx.x, lane = tid & 63, w = tid >> 6;
  const int lin = blockIdx.x + blockIdx.y * 8;
  const int sw  = (lin & 7) * 64 + (lin >> 3);
  const int tile_n = (sw & 7) * 128;
  const int tile_m = (sw >> 3) * 64;
  __shared__ __align__(16) bf16 As[64 * 64];    // 8 KB
  __shared__ __align__(16) bf16 Bs[128 * 64];   // 16 KB

  f32x4 acc[4][2];
#pragma unroll
  for (int i = 0; i < 4; i++)
#pragma unroll
    for (int j = 0; j < 2; j++) acc[i][j] = f32x4{0.f, 0.f, 0.f, 0.f};

  const int quad = lane >> 4, l15 = lane & 15;
  const int srow8 = lane >> 3, p8 = lane & 7;
  const int csrc = p8 ^ srow8;

  for (int k0 = 0; k0 < EMB; k0 += 64) {
#pragma unroll
    for (int i = 0; i < 2; i++) {
      const int ii = w * 2 + i;            // 0..7
      const int r  = ii * 8 + srow8;       // A row 0..63
      gl_lds16(X + (size_t)(tile_m + r) * EMB + k0 + csrc * 8, As + ii * 512);
    }
#pragma unroll
    for (int i = 0; i < 4; i++) {
      const int ii = w * 4 + i;            // 0..15
      const int r  = ii * 8 + srow8;       // B row 0..127
      gl_lds16(W + (size_t)(tile_n + r) * EMB + k0 + csrc * 8, Bs + ii * 512);
    }
    __syncthreads();

#pragma unroll
    for (int kk = 0; kk < 2; kk++) {
      bf16x8 af[4], bfr[2];
#pragma unroll
      for (int mt = 0; mt < 4; mt++) {
        int ml = mt * 16 + l15;
        af[mt] = *(const bf16x8*)(As + ml * 64 + (((kk * 4 + quad) ^ (ml & 7)) & 7) * 8);
      }
#pragma unroll
      for (int nt = 0; nt < 2; nt++) {
        int nl = w * 32 + nt * 16 + l15;
        bfr[nt] = *(const bf16x8*)(Bs + nl * 64 + (((kk * 4 + quad) ^ (nl & 7)) & 7) * 8);
      }
#pragma unroll
      for (int mt = 0; mt < 4; mt++)
#pragma unroll
        for (int nt = 0; nt < 2; nt++)
          acc[mt][nt] = mfma16(af[mt], bfr[nt], acc[mt][nt]);
    }
    __syncthreads();
  }

#pragma unroll
  for (int nt = 0; nt < 2; nt++) {
    const int n = tile_n + w * 32 + nt * 16 + l15;
    const float bias = Bb[n];
#pragma unroll
    for (int mt = 0; mt < 4; mt++) {
#pragma unroll
      for (int r = 0; r < 4; r++) {
        const int m = tile_m + mt * 16 + quad * 4 + r;
        Out[(size_t)m * EMB + n] = acc[mt][nt][r] + bias;
      }
    }
  }
}

// Flash attention v13 = v12 mechanisms at HALF tile size for 2x occupancy:
// KVBLK=64 (two 16KB LDS buffers = 32KB) and 64-q blocks (grid 1024) ->
// 4 blocks/CU, ~16 waves/CU (v12: 2 blocks, 8 waves). All verified pieces
// unchanged: K/V staged via global_load_lds (global-direct failed in v8/v11),
// single XOR-swizzle staging formula (both tiles now 64 rows x 8 chunks,
// 2-way banks = free), swapped-QK lane-local P, pre-permuted V single-b128
// (G = t2*4+quad spans exactly the 8 chunks/row), ones-MFMA row-sum,
// 1 barrier/kt, XCD swizzle (128-block chunks = 4 heads per XCD).
__global__ __launch_bounds__(256) void flash_kernel(
    const bf16* __restrict__ Q,   // [bh][s][d], pre-scaled by log2(e)/8
    const bf16* __restrict__ Kk,  // [bh][s][d]
    const bf16* __restrict__ Vt,  // [bh][d][s], 32-s blocks permuted
    bf16* __restrict__ O)         // [b*S + s][h*64 + d]
{
  const int lin = blockIdx.x + blockIdx.y * 32;   // grid (32,32)
  const int sw  = (lin & 7) * 128 + (lin >> 3);   // 8 XCDs x 128-block chunks
  const int bh  = sw >> 5;                        // 4 heads per XCD chunk
  const int qt  = sw & 31;                        // 64-row q tile
  const int tid = threadIdx.x, lane = tid & 63, w = tid >> 6;
  const int quad = lane >> 4, l15 = lane & 15;

  __shared__ __align__(16) unsigned char smem[32768];
  // buf b at smem + b*16384: [Ks 8KB: 64 krow x 64 d, chunk8^(row&7)]
  //                          [Vs 8KB: 64 d x 64 s,   chunk8^(d&7)]

  const bf16* qbase = Q  + (size_t)bh * SEQ * HD;
  const bf16* kbase = Kk + (size_t)bh * SEQ * HD;
  const bf16* vbase = Vt + (size_t)bh * HD * SEQ;

  // stage one 64-k K/V tile (both tiles 64 rows x 128B: one formula)
  auto stage = [&](int kt, int buf) {
    bf16* Ks = (bf16*)(smem + buf * 16384);
    bf16* Vs = Ks + 4096;
#pragma unroll
    for (int i = 0; i < 2; i++) {
      int r = w * 16 + i * 8 + (lane >> 3);             // row 0..63
      int c = (lane & 7) ^ (r & 7);
      gl_lds16(kbase + (size_t)(kt * 64 + r) * HD + c * 8, Ks + (w * 16 + i * 8) * 64);
      gl_lds16(vbase + (size_t)r * SEQ + kt * 64 + c * 8, Vs + (w * 16 + i * 8) * 64);
    }
  };

  stage(0, 0);

  // this wave's 16 q rows (B-frag: col = l15, k-slots = quad*8+j)
  bf16x8 qf[2];
#pragma unroll
  for (int t = 0; t < 2; t++)
    qf[t] = *(const bf16x8*)(qbase + (size_t)(qt * 64 + w * 16 + l15) * HD
                             + t * 32 + quad * 8);

  bf16x8 ones;
#pragma unroll
  for (int i = 0; i < 8; i++) ones[i] = (bf16)1.0f;

  f32x4 lacc = f32x4{0.f, 0.f, 0.f, 0.f};
  f32x4 oacc[4];
#pragma unroll
  for (int i = 0; i < 4; i++) oacc[i] = f32x4{0.f, 0.f, 0.f, 0.f};

  __syncthreads();

  for (int kt = 0; kt < SEQ / 64; kt++) {
    const int buf = kt & 1;
    if (kt + 1 < SEQ / 64) stage(kt + 1, buf ^ 1);   // prefetch next tile
    const bf16* Ks = (const bf16*)(smem + buf * 16384);
    const bf16* Vs = Ks + 4096;

    __builtin_amdgcn_s_setprio(1);
#pragma unroll
    for (int t2 = 0; t2 < 2; t2++) {
      // S^T for k-block t2*32..t2*32+31: lane holds P[k][q=l15]
      bf16x8 pa;
#pragma unroll
      for (int hh = 0; hh < 2; hh++) {
        const int krow = (t2 * 2 + hh) * 16 + l15;     // A-frag: row = l15
        const int swz = krow & 7;
        bf16x8 kf0 = *(const bf16x8*)(Ks + krow * 64 + ((quad ^ swz) & 7) * 8);
        bf16x8 kf1 = *(const bf16x8*)(Ks + krow * 64 + (((4 + quad) ^ swz) & 7) * 8);
        f32x4 s = f32x4{0.f, 0.f, 0.f, 0.f};
        s = mfma16(kf0, qf[0], s);
        s = mfma16(kf1, qf[1], s);
#pragma unroll
        for (int r = 0; r < 4; r++)
          pa[hh * 4 + r] = (bf16)__builtin_amdgcn_exp2f(s[r]);
      }
      // PV: V pre-permuted so the b128 at chunk (t2*4+quad)^(d&7) holds
      // k = t2*32 + (j>>2)*16 + quad*4 + (j&3) at slot j — matching pa.
#pragma unroll
      for (int dt = 0; dt < 4; dt++) {
        const int d = dt * 16 + l15;
        bf16x8 vv = *(const bf16x8*)(Vs + d * 64 + (((t2 * 4 + quad) ^ (d & 7)) & 7) * 8);
        oacc[dt] = mfma16(vv, pa, oacc[dt]);
      }
      // row-sum on the MFMA pipe
      lacc = mfma16(ones, pa, lacc);
    }
    __builtin_amdgcn_s_setprio(0);
    __syncthreads();   // one barrier/kt: prefetch landed + buf free
  }

  const float rls = __builtin_amdgcn_rcpf(lacc[0]);

  // O^T block: oacc[dt][r] = O[q = l15][d = dt*16+quad*4+r]
  const int b = bh >> 4, h = bh & 15;
  const int srow = qt * 64 + w * 16 + l15;
  bf16* orow = O + ((size_t)(b * SEQ + srow)) * EMB + h * HD;
#pragma unroll
  for (int dt = 0; dt < 4; dt++) {
    bf16x4 ov;
#pragma unroll
    for (int r = 0; r < 4; r++) ov[r] = (bf16)(oacc[dt][r] * rls);
    *(bf16x4*)(orow + dt * 16 + quad * 4) = ov;      // packed 8B store
  }
}

extern "C" void kernel_launch(void* const* d_in, const int* in_sizes, int n_in,
                              void* d_out, int out_size, void* d_ws, size_t ws_size,
                              hipStream_t stream) {
  const float* x  = (const float*)d_in[0];
  const float* Wq = (const float*)d_in[1];
  const float* bq = (const float*)d_in[2];
  const float* Wk = (const float*)d_in[3];
  const float* bk = (const float*)d_in[4];
  const float* Wv = (const float*)d_in[5];
  const float* bv = (const float*)d_in[6];
  const float* Wo = (const float*)d_in[7];
  const float* bo = (const float*)d_in[8];

  const size_t XN = (size_t)MTOT * EMB;  // 4,194,304
  const size_t WN = (size_t)EMB * EMB;   // 1,048,576

  bf16* xb = (bf16*)d_ws;                // [xb | wq | wk | wv | wo] contiguous
  bf16* wq = xb + XN;
  bf16* wk = wq + WN;
  bf16* wv = wk + WN;
  bf16* wo = wv + WN;
  bf16* q  = wo + WN;
  bf16* k  = q + XN;
  bf16* vt = k + XN;
  bf16* at = vt + XN;
  float2* tab = (float2*)(at + XN);      // 2048 x 32 float2 = 512 KB
  float* out = (float*)d_out;

  dim3 blk(256);
  rope_tab_kernel<<<dim3(256), blk, 0, stream>>>(tab);
  cvt_all_kernel<<<dim3(512, 8), blk, 0, stream>>>(x, Wq, Wk, Wv, Wo, xb);

  gemm_kernel<<<dim3(8, 32, 3), blk, 0, stream>>>(
      xb, wq, wk, wv, bq, bk, bv, tab, q, k, vt);
  flash_kernel<<<dim3(32, 32), blk, 0, stream>>>(q, k, vt, at);
  gemm_o_kernel<<<dim3(8, 64), blk, 0, stream>>>(at, wo, bo, out);
}

// Round 9
// 190.746 us; speedup vs baseline: 1.0680x; 1.0680x over previous
//
#include <hip/hip_runtime.h>
#include <hip/hip_bf16.h>
#include <math.h>

typedef __bf16 bf16;
typedef __bf16 bf16x4 __attribute__((ext_vector_type(4)));
typedef __bf16 bf16x8 __attribute__((ext_vector_type(8)));
typedef float f32x4 __attribute__((ext_vector_type(4)));

#define SEQ  2048
#define EMB  1024
#define NH   16
#define HD   64
#define MTOT 4096  // B*S

__device__ __forceinline__ void gl_lds16(const void* g, void* l) {
  __builtin_amdgcn_global_load_lds(
      (const __attribute__((address_space(1))) void*)g,
      (__attribute__((address_space(3))) void*)l, 16, 0, 0);
}

__device__ __forceinline__ f32x4 mfma16(bf16x8 a, bf16x8 b, f32x4 c) {
  return __builtin_amdgcn_mfma_f32_16x16x32_bf16(a, b, c, 0, 0, 0);
}

// log2(10000)/32
#define ROPE_C 0.41524101186092026f
// log2(e)/8 — QK scale, pre-folded into q at the projection epilogue
#define QSCL  0.1803368801111244f

// f32 -> bf16: 8 uniform WN-sized slices; y 0..3 = x chunks, y 4..7 = Wq..Wo.
__global__ __launch_bounds__(256) void cvt_all_kernel(
    const float* __restrict__ x,
    const float* __restrict__ w0, const float* __restrict__ w1,
    const float* __restrict__ w2, const float* __restrict__ w3,
    bf16* __restrict__ dst) {
  const int y = blockIdx.y;
  const size_t WN = (size_t)EMB * EMB;
  const float* src = (y < 4) ? (x + (size_t)y * WN)
                   : (y == 4) ? w0 : (y == 5) ? w1 : (y == 6) ? w2 : w3;
  size_t i = ((size_t)blockIdx.x * 256 + threadIdx.x) * 8;
  float4 a = *(const float4*)(src + i);
  float4 b = *(const float4*)(src + i + 4);
  bf16x8 o;
  o[0] = (bf16)a.x; o[1] = (bf16)a.y; o[2] = (bf16)a.z; o[3] = (bf16)a.w;
  o[4] = (bf16)b.x; o[5] = (bf16)b.y; o[6] = (bf16)b.z; o[7] = (bf16)b.w;
  *(bf16x8*)(dst + (size_t)y * WN + i) = o;
}

// QKV projection (unfused z, 128x128 tile, BK=64): z = blockIdx.z selects
// {q,k,v}. BK=64 halves the barrier/vmcnt(0)-drain count vs BK=32 (the m97
// structural stall) at UNCHANGED occupancy. Swizzle (both-sides, rule 21):
// LDS slot p of row r holds chunk p^(r&7); read uses chunk (kk*4+quad)^(ml&7).
// RoPE on q,k via inline sincos (table variant measured SLOWER in R8);
// q pre-scaled by QSCL. q,k -> [bh][s][d]; v -> [bh][d][s] with each 32-s
// block PERMUTED for flash's single-b128 PV fragment.
__global__ __launch_bounds__(256) void gemm_kernel(
    const bf16* __restrict__ X,
    const bf16* __restrict__ W0, const bf16* __restrict__ W1, const bf16* __restrict__ W2,
    const float* __restrict__ B0, const float* __restrict__ B1, const float* __restrict__ B2,
    bf16* __restrict__ Oq, bf16* __restrict__ Ok, bf16* __restrict__ Ovt)
{
  const int K = EMB;
  const int tid  = threadIdx.x;
  const int lane = tid & 63;
  const int w    = tid >> 6;       // wave 0..3
  const int wm   = w >> 1, wn = w & 1;
  // XCD swizzle within each z-slice: 32-block chunks per XCD.
  const int lin = blockIdx.x + blockIdx.y * 8;
  const int sw  = (lin & 7) * 32 + (lin >> 3);
  const int tile_n = (sw & 7) * 128;
  const int tile_m = (sw >> 3) * 128;
  const int z = blockIdx.z;
  const bf16*  Wsel = (z == 0) ? W0 : (z == 1 ? W1 : W2);
  const float* Bsel = (z == 0) ? B0 : (z == 1 ? B1 : B2);

  __shared__ __align__(16) unsigned char smem[33792];  // staging 32KB | CS 33792
  bf16* As = (bf16*)smem;            // 128 x 64 = 16 KB
  bf16* Bs = (bf16*)(smem + 16384);  // 128 x 64 = 16 KB

  f32x4 acc[4][4];
#pragma unroll
  for (int i = 0; i < 4; i++)
#pragma unroll
    for (int j = 0; j < 4; j++) acc[i][j] = f32x4{0.f, 0.f, 0.f, 0.f};

  const int quad  = lane >> 4;
  const int l15   = lane & 15;
  const int srow8 = lane >> 3;   // row within an 8-row staging issue
  const int p8    = lane & 7;    // 16B-chunk slot within the 128B row
  const int csrc  = p8 ^ srow8;  // global chunk feeding this LDS slot

  for (int k0 = 0; k0 < K; k0 += 64) {
#pragma unroll
    for (int i = 0; i < 4; i++) {
      const int ii = w * 4 + i;            // 8-row group 0..15
      const int r  = ii * 8 + srow8;       // tile-local row 0..127
      gl_lds16(X    + (size_t)(tile_m + r) * K + k0 + csrc * 8, As + ii * 512);
      gl_lds16(Wsel + (size_t)(tile_n + r) * K + k0 + csrc * 8, Bs + ii * 512);
    }
    __syncthreads();

#pragma unroll
    for (int kk = 0; kk < 2; kk++) {
      bf16x8 af[4], bfr[4];
#pragma unroll
      for (int mt = 0; mt < 4; mt++) {
        int ml = wm * 64 + mt * 16 + l15;
        af[mt] = *(const bf16x8*)(As + ml * 64 + (((kk * 4 + quad) ^ (ml & 7)) & 7) * 8);
      }
#pragma unroll
      for (int nt = 0; nt < 4; nt++) {
        int nl = wn * 64 + nt * 16 + l15;
        bfr[nt] = *(const bf16x8*)(Bs + nl * 64 + (((kk * 4 + quad) ^ (nl & 7)) & 7) * 8);
      }
#pragma unroll
      for (int mt = 0; mt < 4; mt++)
#pragma unroll
        for (int nt = 0; nt < 4; nt++)
          acc[mt][nt] = mfma16(af[mt], bfr[nt], acc[mt][nt]);
    }
    __syncthreads();
  }

  // ---- epilogue ----
  bf16* CS = (bf16*)smem;  // 128 rows x 132 stride
  const int b = tile_m >> 11;
  const int s0 = tile_m & (SEQ - 1);

  if (z < 2) {
    // bias + RoPE in registers, stage CS[m][n]
#pragma unroll
    for (int nt = 0; nt < 4; nt++) {
      const int nl = wn * 64 + nt * 16 + l15;
      const int n = tile_n + nl;
      const float bias = Bsel[n];
      const int j = n & 31;
      const float invf = exp2f(-(float)j * ROPE_C);
#pragma unroll
      for (int mt = 0; mt < 4; mt++) {
#pragma unroll
        for (int r = 0; r < 4; r++) {
          const int ml = wm * 64 + mt * 16 + quad * 4 + r;
          float a = acc[mt][nt][r] + bias;
          float p = __shfl_xor(a, 1, 64);  // partner at d^1 (incl. its bias)
          float th = (float)(s0 + ml) * invf;
          float sn, cs;
          __sincosf(th, &sn, &cs);
          float res = (n & 1) ? fmaf(p, sn, a * cs) : fmaf(-p, sn, a * cs);
          if (z == 0) res *= QSCL;  // fold QK scale+log2e into q
          CS[ml * 132 + nl] = (bf16)res;
        }
      }
    }
    __syncthreads();
    // coalesced store: 256 rows (2 heads x 128 s), 128 B each
    bf16* Odst = (z == 0) ? Oq : Ok;
#pragma unroll
    for (int g = 0; g < 8; g++) {
      int unit = g * 256 + tid;
      int chunk = unit & 7;          // 16B chunk within row
      int row = unit >> 3;           // 0..255
      int hl = row >> 7, sl = row & 127;
      bf16x8 v = *(const bf16x8*)(CS + sl * 132 + hl * 64 + chunk * 8);
      int hg = (tile_n >> 6) + hl;
      size_t o = ((size_t)(b * NH + hg) * SEQ + s0 + sl) * HD + chunk * 8;
      *(bf16x8*)(Odst + o) = v;
    }
  } else {
    // V^T: stage CS[n][perm(m)] — permute s within each 32-block so flash's
    // per-lane fragment (k = hf*16 + quad*4 + e -> pos quad*8 + hf*4 + e) is
    // contiguous 16B.
#pragma unroll
    for (int nt = 0; nt < 4; nt++) {
      const int nl = wn * 64 + nt * 16 + l15;
      const float bias = Bsel[tile_n + nl];
#pragma unroll
      for (int mt = 0; mt < 4; mt++) {
        const int mb = wm * 64 + mt * 16 + quad * 4;
#pragma unroll
        for (int r = 0; r < 4; r++) {
          const int ml = mb + r;
          const int mp = (ml & ~31) | ((ml & 12) << 1) | ((ml & 16) >> 2) | (ml & 3);
          CS[nl * 132 + mp] = (bf16)(acc[mt][nt][r] + bias);
        }
      }
    }
    __syncthreads();
    // coalesced store: 128 rows (d), 256 B each
#pragma unroll
    for (int g = 0; g < 8; g++) {
      int unit = g * 256 + tid;
      int chunk = unit & 15;         // 16B chunk within row
      int row = unit >> 4;           // 0..127 (n_local)
      bf16x8 v = *(const bf16x8*)(CS + row * 132 + chunk * 8);
      int nglob = tile_n + row;
      int d = nglob & 63, hg = nglob >> 6;
      size_t o = ((size_t)(b * NH + hg) * HD + d) * SEQ + s0 + chunk * 8;
      *(bf16x8*)(Ovt + o) = v;
    }
  }
}

// Out projection v2: 64x128 tiles, BK=128 (8 vmcnt drains instead of 16,
// 32 MFMA/wave per drain), 512 blocks = 2/CU (grid-limited; LDS 48 KB still
// allows 3 so occupancy unchanged). 16-chunk XOR swizzle = the verified
// flash-v10 Vs pattern (2-way banks = free). Epilogue stages f32 through LDS
// and emits coalesced float4 stores (8/thread vs 32 scalar dwords).
__global__ __launch_bounds__(256) void gemm_o_kernel(
    const bf16* __restrict__ X,     // attn out [4096][1024] bf16
    const bf16* __restrict__ W,     // Wo [1024][1024] bf16
    const float* __restrict__ Bb,   // bo
    float* __restrict__ Out)        // [4096][1024] f32
{
  const int tid = threadIdx.x, lane = tid & 63, w = tid >> 6;
  const int lin = blockIdx.x + blockIdx.y * 8;
  const int sw  = (lin & 7) * 64 + (lin >> 3);
  const int tile_n = (sw & 7) * 128;
  const int tile_m = (sw >> 3) * 64;
  __shared__ __align__(16) unsigned char smem[49152];
  bf16* As = (bf16*)smem;             // 64 x 128 = 16 KB
  bf16* Bs = (bf16*)(smem + 16384);   // 128 x 128 = 32 KB

  f32x4 acc[4][2];
#pragma unroll
  for (int i = 0; i < 4; i++)
#pragma unroll
    for (int j = 0; j < 2; j++) acc[i][j] = f32x4{0.f, 0.f, 0.f, 0.f};

  const int quad = lane >> 4, l15 = lane & 15;
  const int srow4 = lane >> 4;       // row within a 4-row staging issue
  const int p16   = lane & 15;       // 16B slot within the 256B row
  const int csrc_base = p16;         // chunk = p16 ^ (r&15)

  for (int k0 = 0; k0 < EMB; k0 += 128) {
#pragma unroll
    for (int i = 0; i < 4; i++) {
      int r = (w * 4 + i) * 4 + srow4;          // A row 0..63
      int c = csrc_base ^ (r & 15);
      gl_lds16(X + (size_t)(tile_m + r) * EMB + k0 + c * 8, As + (w * 4 + i) * 512);
    }
#pragma unroll
    for (int i = 0; i < 8; i++) {
      int r = (w * 8 + i) * 4 + srow4;          // B row 0..127
      int c = csrc_base ^ (r & 15);
      gl_lds16(W + (size_t)(tile_n + r) * EMB + k0 + c * 8, Bs + (w * 8 + i) * 512);
    }
    __syncthreads();

#pragma unroll
    for (int kk = 0; kk < 4; kk++) {
      bf16x8 af[4], bfr[2];
#pragma unroll
      for (int mt = 0; mt < 4; mt++) {
        int ml = mt * 16 + l15;
        af[mt] = *(const bf16x8*)(As + ml * 128 + (((kk * 4 + quad) ^ (ml & 15)) & 15) * 8);
      }
#pragma unroll
      for (int nt = 0; nt < 2; nt++) {
        int nl = w * 32 + nt * 16 + l15;
        bfr[nt] = *(const bf16x8*)(Bs + nl * 128 + (((kk * 4 + quad) ^ (nl & 15)) & 15) * 8);
      }
#pragma unroll
      for (int mt = 0; mt < 4; mt++)
#pragma unroll
        for (int nt = 0; nt < 2; nt++)
          acc[mt][nt] = mfma16(af[mt], bfr[nt], acc[mt][nt]);
    }
    __syncthreads();
  }

  // ---- epilogue: bias + LDS-staged coalesced float4 stores ----
  float* CSf = (float*)smem;          // 64 rows x 132 f32 stride = 33792 B
#pragma unroll
  for (int nt = 0; nt < 2; nt++) {
    const int nl = w * 32 + nt * 16 + l15;
    const float bias = Bb[tile_n + nl];
#pragma unroll
    for (int mt = 0; mt < 4; mt++)
#pragma unroll
      for (int r = 0; r < 4; r++)
        CSf[(mt * 16 + quad * 4 + r) * 132 + nl] = acc[mt][nt][r] + bias;
  }
  __syncthreads();
#pragma unroll
  for (int g = 0; g < 8; g++) {
    int unit = g * 256 + tid;
    int chunk = unit & 31;            // 16B (4 f32) chunk within 512B row
    int row = unit >> 5;              // 0..63
    float4 v = *(const float4*)(CSf + row * 132 + chunk * 4);
    *(float4*)(Out + (size_t)(tile_m + row) * EMB + tile_n + chunk * 4) = v;
  }
}

// Flash attention v12 (R7-verified best): LDS double-buffered K/V (KVBLK=128)
// via global_load_lds, 1 barrier/kt, swapped-QK^T lane-local P, pre-permuted
// V single-b128 PV (zero conflicts), XCD swizzle, setprio, ones-MFMA row-sum
// (denominator uses the same bf16-rounded P as the numerator).
__global__ __launch_bounds__(256) void flash_kernel(
    const bf16* __restrict__ Q,   // [bh][s][d], pre-scaled by log2(e)/8
    const bf16* __restrict__ Kk,  // [bh][s][d]
    const bf16* __restrict__ Vt,  // [bh][d][s], 32-s blocks permuted
    bf16* __restrict__ O)         // [b*S + s][h*64 + d]
{
  const int lin = blockIdx.x + blockIdx.y * 16;   // dispatch-linear, x fastest
  const int sw  = (lin & 7) * 64 + (lin >> 3);    // 8 XCDs x 64-block chunks
  const int bh  = sw >> 4;                        // 4 heads per XCD chunk
  const int qt  = sw & 15;                        // 128-row q tile
  const int tid = threadIdx.x, lane = tid & 63, w = tid >> 6;
  const int quad = lane >> 4, l15 = lane & 15;

  __shared__ __align__(16) unsigned char smem[65536];
  // buf b at smem + b*32768: [Ks 16KB: 128 krow x 64 d, chunk8^(row&7)]
  //                          [Vs 16KB:  64 d x 128 s,  chunk16^(d&15)]

  const bf16* qbase = Q  + (size_t)bh * SEQ * HD;
  const bf16* kbase = Kk + (size_t)bh * SEQ * HD;
  const bf16* vbase = Vt + (size_t)bh * HD * SEQ;

  // stage one K/V tile into buffer `buf` (zero-conflict pattern)
  auto stage = [&](int kt, int buf) {
    bf16* Ks = (bf16*)(smem + buf * 32768);
    bf16* Vs = Ks + 8192;
#pragma unroll
    for (int i = 0; i < 4; i++) {
      int r = w * 32 + i * 8 + (lane >> 3);             // K row 0..127
      int c = (lane & 7) ^ (r & 7);
      gl_lds16(kbase + (size_t)(kt * 128 + r) * HD + c * 8, Ks + (w * 32 + i * 8) * 64);
      int dv = w * 16 + i * 4 + (lane >> 4);            // V^T row (d) 0..63
      int cv = (lane & 15) ^ (dv & 15);
      gl_lds16(vbase + (size_t)dv * SEQ + kt * 128 + cv * 8, Vs + (w * 16 + i * 4) * 128);
    }
  };

  stage(0, 0);

  // preload this wave's 32 q rows (B-frag layout: col = l15, k = quad*8+j)
  bf16x8 qf[2][2];
#pragma unroll
  for (int m = 0; m < 2; m++)
#pragma unroll
    for (int t = 0; t < 2; t++)
      qf[m][t] = *(const bf16x8*)(qbase + (size_t)(qt * 128 + w * 32 + m * 16 + l15) * HD
                                  + t * 32 + quad * 8);

  // all-ones A-fragment for the row-sum MFMA
  bf16x8 ones;
#pragma unroll
  for (int i = 0; i < 8; i++) ones[i] = (bf16)1.0f;

  f32x4 lacc[2];
  f32x4 oacc[2][4];
#pragma unroll
  for (int m = 0; m < 2; m++) {
    lacc[m] = f32x4{0.f, 0.f, 0.f, 0.f};
#pragma unroll
    for (int i = 0; i < 4; i++) oacc[m][i] = f32x4{0.f, 0.f, 0.f, 0.f};
  }

  __syncthreads();

  for (int kt = 0; kt < SEQ / 128; kt++) {
    const int buf = kt & 1;
    if (kt + 1 < SEQ / 128) stage(kt + 1, buf ^ 1);   // prefetch next tile
    const bf16* Ks = (const bf16*)(smem + buf * 32768);
    const bf16* Vs = Ks + 8192;

    __builtin_amdgcn_s_setprio(1);
#pragma unroll
    for (int t2 = 0; t2 < 4; t2++) {
      // S^T for k-block t2*32..t2*32+31: lane holds P[k=mk*16+quad*4+r][q=l15]
      bf16x8 pa[2];
#pragma unroll
      for (int hh = 0; hh < 2; hh++) {
        const int krow = (t2 * 2 + hh) * 16 + l15;     // A-frag: row = l15
        const int swz = krow & 7;
        bf16x8 kf0 = *(const bf16x8*)(Ks + krow * 64 + ((quad ^ swz) & 7) * 8);
        bf16x8 kf1 = *(const bf16x8*)(Ks + krow * 64 + (((4 + quad) ^ swz) & 7) * 8);
#pragma unroll
        for (int mq = 0; mq < 2; mq++) {
          f32x4 s = f32x4{0.f, 0.f, 0.f, 0.f};
          s = mfma16(kf0, qf[mq][0], s);
          s = mfma16(kf1, qf[mq][1], s);
#pragma unroll
          for (int r = 0; r < 4; r++)
            pa[mq][hh * 4 + r] = (bf16)__builtin_amdgcn_exp2f(s[r]);
        }
      }
      // PV: V pre-permuted so the b128 at chunk (t2*4+quad)^l15 holds exactly
      // k = t2*32 + (j>>2)*16 + quad*4 + (j&3) at slot j — matching pa.
#pragma unroll
      for (int dt = 0; dt < 4; dt++) {
        const int d = dt * 16 + l15;
        bf16x8 vv = *(const bf16x8*)(Vs + d * 128 + ((t2 * 4 + quad) ^ l15) * 8);
#pragma unroll
        for (int mq = 0; mq < 2; mq++)
          oacc[mq][dt] = mfma16(vv, pa[mq], oacc[mq][dt]);
      }
      // row-sum on the MFMA pipe: every output row = sum_k pa[k][q=l15]
#pragma unroll
      for (int mq = 0; mq < 2; mq++)
        lacc[mq] = mfma16(ones, pa[mq], lacc[mq]);
    }
    __builtin_amdgcn_s_setprio(0);
    __syncthreads();   // one barrier/kt: prefetch landed + buf free to overwrite
  }

  // rls straight from lacc (all 4 rows identical; no cross-lane reduce needed)
  float rls[2];
#pragma unroll
  for (int mq = 0; mq < 2; mq++)
    rls[mq] = __builtin_amdgcn_rcpf(lacc[mq][0]);

  // O^T blocks: oacc[mq][dt][r] = O[q = mq*16+l15][d = dt*16+quad*4+r]
  const int b = bh >> 4, h = bh & 15;
#pragma unroll
  for (int mq = 0; mq < 2; mq++) {
    const int srow = qt * 128 + w * 32 + mq * 16 + l15;
    bf16* orow = O + ((size_t)(b * SEQ + srow)) * EMB + h * HD;
#pragma unroll
    for (int dt = 0; dt < 4; dt++) {
      bf16x4 ov;
#pragma unroll
      for (int r = 0; r < 4; r++) ov[r] = (bf16)(oacc[mq][dt][r] * rls[mq]);
      *(bf16x4*)(orow + dt * 16 + quad * 4) = ov;      // packed 8B store
    }
  }
}

extern "C" void kernel_launch(void* const* d_in, const int* in_sizes, int n_in,
                              void* d_out, int out_size, void* d_ws, size_t ws_size,
                              hipStream_t stream) {
  const float* x  = (const float*)d_in[0];
  const float* Wq = (const float*)d_in[1];
  const float* bq = (const float*)d_in[2];
  const float* Wk = (const float*)d_in[3];
  const float* bk = (const float*)d_in[4];
  const float* Wv = (const float*)d_in[5];
  const float* bv = (const float*)d_in[6];
  const float* Wo = (const float*)d_in[7];
  const float* bo = (const float*)d_in[8];

  const size_t XN = (size_t)MTOT * EMB;  // 4,194,304
  const size_t WN = (size_t)EMB * EMB;   // 1,048,576

  bf16* xb = (bf16*)d_ws;                // [xb | wq | wk | wv | wo] contiguous
  bf16* wq = xb + XN;
  bf16* wk = wq + WN;
  bf16* wv = wk + WN;
  bf16* wo = wv + WN;
  bf16* q  = wo + WN;
  bf16* k  = q + XN;
  bf16* vt = k + XN;
  bf16* at = vt + XN;
  float* out = (float*)d_out;

  dim3 blk(256);
  cvt_all_kernel<<<dim3(512, 8), blk, 0, stream>>>(x, Wq, Wk, Wv, Wo, xb);

  gemm_kernel<<<dim3(8, 32, 3), blk, 0, stream>>>(
      xb, wq, wk, wv, bq, bk, bv, q, k, vt);
  flash_kernel<<<dim3(16, 32), blk, 0, stream>>>(q, k, vt, at);
  gemm_o_kernel<<<dim3(8, 64), blk, 0, stream>>>(at, wo, bo, out);
}

// Round 10
// 179.220 us; speedup vs baseline: 1.1367x; 1.0643x over previous
//
#include <hip/hip_runtime.h>
#include <hip/hip_bf16.h>
#include <math.h>

typedef __bf16 bf16;
typedef __bf16 bf16x4 __attribute__((ext_vector_type(4)));
typedef __bf16 bf16x8 __attribute__((ext_vector_type(8)));
typedef float f32x4 __attribute__((ext_vector_type(4)));

#define SEQ  2048
#define EMB  1024
#define NH   16
#define HD   64
#define MTOT 4096  // B*S

__device__ __forceinline__ void gl_lds16(const void* g, void* l) {
  __builtin_amdgcn_global_load_lds(
      (const __attribute__((address_space(1))) void*)g,
      (__attribute__((address_space(3))) void*)l, 16, 0, 0);
}

__device__ __forceinline__ f32x4 mfma16(bf16x8 a, bf16x8 b, f32x4 c) {
  return __builtin_amdgcn_mfma_f32_16x16x32_bf16(a, b, c, 0, 0, 0);
}

// log2(10000)/32
#define ROPE_C 0.41524101186092026f
// log2(e)/8 — QK scale, pre-folded into q at the projection epilogue
#define QSCL  0.1803368801111244f

// f32 -> bf16: 8 uniform WN-sized slices; y 0..3 = x chunks, y 4..7 = Wq..Wo.
__global__ __launch_bounds__(256) void cvt_all_kernel(
    const float* __restrict__ x,
    const float* __restrict__ w0, const float* __restrict__ w1,
    const float* __restrict__ w2, const float* __restrict__ w3,
    bf16* __restrict__ dst) {
  const int y = blockIdx.y;
  const size_t WN = (size_t)EMB * EMB;
  const float* src = (y < 4) ? (x + (size_t)y * WN)
                   : (y == 4) ? w0 : (y == 5) ? w1 : (y == 6) ? w2 : w3;
  size_t i = ((size_t)blockIdx.x * 256 + threadIdx.x) * 8;
  float4 a = *(const float4*)(src + i);
  float4 b = *(const float4*)(src + i + 4);
  bf16x8 o;
  o[0] = (bf16)a.x; o[1] = (bf16)a.y; o[2] = (bf16)a.z; o[3] = (bf16)a.w;
  o[4] = (bf16)b.x; o[5] = (bf16)b.y; o[6] = (bf16)b.z; o[7] = (bf16)b.w;
  *(bf16x8*)(dst + (size_t)y * WN + i) = o;
}

// QKV projection v3 (unfused z, 128m x 64n tile, BK=64): 1536 blocks ->
// ~6 blocks/CU (vs 3 with the 128x128 tile) — the grid, not resources, was
// capping occupancy; more independent blocks per CU overlap the per-block
// vmcnt(0) barrier drains (the m97-structure stall). LDS 24.6 KB/block,
// acc 4x2. Staging + fragment swizzle formulas unchanged (both-sides XOR,
// rule 21). Epilogues are the 128x64 single-head versions verified in the
// R4 fused-kernel run (q/k: stride-72 CS + RoPE; v: stride-132 CS + 32-s
// block permute for flash's single-b128 PV fragment). q pre-scaled by QSCL.
__global__ __launch_bounds__(256) void gemm_kernel(
    const bf16* __restrict__ X,
    const bf16* __restrict__ W0, const bf16* __restrict__ W1, const bf16* __restrict__ W2,
    const float* __restrict__ B0, const float* __restrict__ B1, const float* __restrict__ B2,
    bf16* __restrict__ Oq, bf16* __restrict__ Ok, bf16* __restrict__ Ovt)
{
  const int K = EMB;
  const int tid  = threadIdx.x;
  const int lane = tid & 63;
  const int w    = tid >> 6;       // wave 0..3
  const int wm   = w >> 1, wn = w & 1;
  // XCD swizzle within each z-slice: 64-block chunks (4 m-tiles x 16 n) per
  // XCD. Bijective: 512 = 8 * 64.
  const int lin = blockIdx.x + blockIdx.y * 16;
  const int sw  = (lin & 7) * 64 + (lin >> 3);
  const int tile_n = (sw & 15) * 64;     // 0..960
  const int tile_m = (sw >> 4) * 128;    // 0..3968
  const int z = blockIdx.z;
  const bf16*  Wsel = (z == 0) ? W0 : (z == 1 ? W1 : W2);
  const float* Bsel = (z == 0) ? B0 : (z == 1 ? B1 : B2);

  __shared__ __align__(16) unsigned char smem[24576];
  bf16* As = (bf16*)smem;            // 128 x 64 = 16 KB
  bf16* Bs = (bf16*)(smem + 16384);  //  64 x 64 =  8 KB

  f32x4 acc[4][2];
#pragma unroll
  for (int i = 0; i < 4; i++)
#pragma unroll
    for (int j = 0; j < 2; j++) acc[i][j] = f32x4{0.f, 0.f, 0.f, 0.f};

  const int quad  = lane >> 4;
  const int l15   = lane & 15;
  const int srow8 = lane >> 3;   // row within an 8-row staging issue
  const int p8    = lane & 7;    // 16B-chunk slot within the 128B row
  const int csrc  = p8 ^ srow8;  // global chunk feeding this LDS slot

  for (int k0 = 0; k0 < K; k0 += 64) {
#pragma unroll
    for (int i = 0; i < 4; i++) {
      const int ii = w * 4 + i;            // 8-row group 0..15
      const int r  = ii * 8 + srow8;       // A row 0..127
      gl_lds16(X + (size_t)(tile_m + r) * K + k0 + csrc * 8, As + ii * 512);
    }
#pragma unroll
    for (int i = 0; i < 2; i++) {
      const int ii = w * 2 + i;            // 8-row group 0..7
      const int r  = ii * 8 + srow8;       // B row 0..63
      gl_lds16(Wsel + (size_t)(tile_n + r) * K + k0 + csrc * 8, Bs + ii * 512);
    }
    __syncthreads();

#pragma unroll
    for (int kk = 0; kk < 2; kk++) {
      bf16x8 af[4], bfr[2];
#pragma unroll
      for (int mt = 0; mt < 4; mt++) {
        int ml = wm * 64 + mt * 16 + l15;
        af[mt] = *(const bf16x8*)(As + ml * 64 + (((kk * 4 + quad) ^ (ml & 7)) & 7) * 8);
      }
#pragma unroll
      for (int nt = 0; nt < 2; nt++) {
        int nl = wn * 32 + nt * 16 + l15;
        bfr[nt] = *(const bf16x8*)(Bs + nl * 64 + (((kk * 4 + quad) ^ (nl & 7)) & 7) * 8);
      }
#pragma unroll
      for (int mt = 0; mt < 4; mt++)
#pragma unroll
        for (int nt = 0; nt < 2; nt++)
          acc[mt][nt] = mfma16(af[mt], bfr[nt], acc[mt][nt]);
    }
    __syncthreads();
  }

  // ---- epilogue (128x64 single-head; verified in the R4 fused run) ----
  bf16* CS = (bf16*)smem;
  const int b  = tile_m >> 11;
  const int s0 = tile_m & (SEQ - 1);
  const int hg = tile_n >> 6;          // tile spans exactly one head

  if (z < 2) {
    // bias + RoPE in registers, stage CS[m][n] stride 72
#pragma unroll
    for (int nt = 0; nt < 2; nt++) {
      const int nl = wn * 32 + nt * 16 + l15;
      const int n = tile_n + nl;
      const float bias = Bsel[n];
      const int j = n & 31;
      const float invf = exp2f(-(float)j * ROPE_C);
#pragma unroll
      for (int mt = 0; mt < 4; mt++) {
#pragma unroll
        for (int r = 0; r < 4; r++) {
          const int ml = wm * 64 + mt * 16 + quad * 4 + r;
          float a = acc[mt][nt][r] + bias;
          float p = __shfl_xor(a, 1, 64);  // partner at d^1 (incl. its bias)
          float th = (float)(s0 + ml) * invf;
          float sn, cs;
          __sincosf(th, &sn, &cs);
          float res = (n & 1) ? fmaf(p, sn, a * cs) : fmaf(-p, sn, a * cs);
          if (z == 0) res *= QSCL;  // fold QK scale+log2e into q
          CS[ml * 72 + nl] = (bf16)res;
        }
      }
    }
    __syncthreads();
    // coalesced copy: 128 rows x 64 cols (one head)
    bf16* Odst = (z == 0) ? Oq : Ok;
#pragma unroll
    for (int g = 0; g < 4; g++) {
      int unit = g * 256 + tid;
      int chunk = unit & 7;          // 16B chunk within row
      int row = unit >> 3;           // 0..127
      bf16x8 v = *(const bf16x8*)(CS + row * 72 + chunk * 8);
      size_t o = ((size_t)(b * NH + hg) * SEQ + s0 + row) * HD + chunk * 8;
      *(bf16x8*)(Odst + o) = v;
    }
  } else {
    // V^T: stage CS[n][perm(m)] stride 132 — permute s within each 32-block
    // so flash's per-lane fragment is contiguous 16B.
#pragma unroll
    for (int nt = 0; nt < 2; nt++) {
      const int nl = wn * 32 + nt * 16 + l15;
      const float bias = Bsel[tile_n + nl];
#pragma unroll
      for (int mt = 0; mt < 4; mt++) {
        const int mb = wm * 64 + mt * 16 + quad * 4;
#pragma unroll
        for (int r = 0; r < 4; r++) {
          const int ml = mb + r;
          const int mp = (ml & ~31) | ((ml & 12) << 1) | ((ml & 16) >> 2) | (ml & 3);
          CS[nl * 132 + mp] = (bf16)(acc[mt][nt][r] + bias);
        }
      }
    }
    __syncthreads();
    // coalesced copy: 64 rows (d) x 256 B
#pragma unroll
    for (int g = 0; g < 4; g++) {
      int unit = g * 256 + tid;
      int chunk = unit & 15;         // 16B chunk within row
      int row = unit >> 4;           // 0..63 (= d, tile spans one head)
      bf16x8 v = *(const bf16x8*)(CS + row * 132 + chunk * 8);
      size_t o = ((size_t)(b * NH + hg) * HD + row) * SEQ + s0 + chunk * 8;
      *(bf16x8*)(Ovt + o) = v;
    }
  }
}

// Out projection v2: 64x128 tiles, BK=128 (8 vmcnt drains), 512 blocks,
// XCD-swizzled, LDS-staged float4 epilogue. (R9: neutral-to-positive; kept.)
__global__ __launch_bounds__(256) void gemm_o_kernel(
    const bf16* __restrict__ X,     // attn out [4096][1024] bf16
    const bf16* __restrict__ W,     // Wo [1024][1024] bf16
    const float* __restrict__ Bb,   // bo
    float* __restrict__ Out)        // [4096][1024] f32
{
  const int tid = threadIdx.x, lane = tid & 63, w = tid >> 6;
  const int lin = blockIdx.x + blockIdx.y * 8;
  const int sw  = (lin & 7) * 64 + (lin >> 3);
  const int tile_n = (sw & 7) * 128;
  const int tile_m = (sw >> 3) * 64;
  __shared__ __align__(16) unsigned char smem[49152];
  bf16* As = (bf16*)smem;             // 64 x 128 = 16 KB
  bf16* Bs = (bf16*)(smem + 16384);   // 128 x 128 = 32 KB

  f32x4 acc[4][2];
#pragma unroll
  for (int i = 0; i < 4; i++)
#pragma unroll
    for (int j = 0; j < 2; j++) acc[i][j] = f32x4{0.f, 0.f, 0.f, 0.f};

  const int quad = lane >> 4, l15 = lane & 15;
  const int srow4 = lane >> 4;       // row within a 4-row staging issue
  const int p16   = lane & 15;       // 16B slot within the 256B row

  for (int k0 = 0; k0 < EMB; k0 += 128) {
#pragma unroll
    for (int i = 0; i < 4; i++) {
      int r = (w * 4 + i) * 4 + srow4;          // A row 0..63
      int c = p16 ^ (r & 15);
      gl_lds16(X + (size_t)(tile_m + r) * EMB + k0 + c * 8, As + (w * 4 + i) * 512);
    }
#pragma unroll
    for (int i = 0; i < 8; i++) {
      int r = (w * 8 + i) * 4 + srow4;          // B row 0..127
      int c = p16 ^ (r & 15);
      gl_lds16(W + (size_t)(tile_n + r) * EMB + k0 + c * 8, Bs + (w * 8 + i) * 512);
    }
    __syncthreads();

#pragma unroll
    for (int kk = 0; kk < 4; kk++) {
      bf16x8 af[4], bfr[2];
#pragma unroll
      for (int mt = 0; mt < 4; mt++) {
        int ml = mt * 16 + l15;
        af[mt] = *(const bf16x8*)(As + ml * 128 + (((kk * 4 + quad) ^ (ml & 15)) & 15) * 8);
      }
#pragma unroll
      for (int nt = 0; nt < 2; nt++) {
        int nl = w * 32 + nt * 16 + l15;
        bfr[nt] = *(const bf16x8*)(Bs + nl * 128 + (((kk * 4 + quad) ^ (nl & 15)) & 15) * 8);
      }
#pragma unroll
      for (int mt = 0; mt < 4; mt++)
#pragma unroll
        for (int nt = 0; nt < 2; nt++)
          acc[mt][nt] = mfma16(af[mt], bfr[nt], acc[mt][nt]);
    }
    __syncthreads();
  }

  // ---- epilogue: bias + LDS-staged coalesced float4 stores ----
  float* CSf = (float*)smem;          // 64 rows x 132 f32 stride = 33792 B
#pragma unroll
  for (int nt = 0; nt < 2; nt++) {
    const int nl = w * 32 + nt * 16 + l15;
    const float bias = Bb[tile_n + nl];
#pragma unroll
    for (int mt = 0; mt < 4; mt++)
#pragma unroll
      for (int r = 0; r < 4; r++)
        CSf[(mt * 16 + quad * 4 + r) * 132 + nl] = acc[mt][nt][r] + bias;
  }
  __syncthreads();
#pragma unroll
  for (int g = 0; g < 8; g++) {
    int unit = g * 256 + tid;
    int chunk = unit & 31;            // 16B (4 f32) chunk within 512B row
    int row = unit >> 5;              // 0..63
    float4 v = *(const float4*)(CSf + row * 132 + chunk * 4);
    *(float4*)(Out + (size_t)(tile_m + row) * EMB + tile_n + chunk * 4) = v;
  }
}

// Flash attention v12 (R7-verified best): LDS double-buffered K/V (KVBLK=128)
// via global_load_lds, 1 barrier/kt, swapped-QK^T lane-local P, pre-permuted
// V single-b128 PV (zero conflicts), XCD swizzle, setprio, ones-MFMA row-sum
// (denominator uses the same bf16-rounded P as the numerator).
__global__ __launch_bounds__(256) void flash_kernel(
    const bf16* __restrict__ Q,   // [bh][s][d], pre-scaled by log2(e)/8
    const bf16* __restrict__ Kk,  // [bh][s][d]
    const bf16* __restrict__ Vt,  // [bh][d][s], 32-s blocks permuted
    bf16* __restrict__ O)         // [b*S + s][h*64 + d]
{
  const int lin = blockIdx.x + blockIdx.y * 16;   // dispatch-linear, x fastest
  const int sw  = (lin & 7) * 64 + (lin >> 3);    // 8 XCDs x 64-block chunks
  const int bh  = sw >> 4;                        // 4 heads per XCD chunk
  const int qt  = sw & 15;                        // 128-row q tile
  const int tid = threadIdx.x, lane = tid & 63, w = tid >> 6;
  const int quad = lane >> 4, l15 = lane & 15;

  __shared__ __align__(16) unsigned char smem[65536];
  // buf b at smem + b*32768: [Ks 16KB: 128 krow x 64 d, chunk8^(row&7)]
  //                          [Vs 16KB:  64 d x 128 s,  chunk16^(d&15)]

  const bf16* qbase = Q  + (size_t)bh * SEQ * HD;
  const bf16* kbase = Kk + (size_t)bh * SEQ * HD;
  const bf16* vbase = Vt + (size_t)bh * HD * SEQ;

  // stage one K/V tile into buffer `buf` (zero-conflict pattern)
  auto stage = [&](int kt, int buf) {
    bf16* Ks = (bf16*)(smem + buf * 32768);
    bf16* Vs = Ks + 8192;
#pragma unroll
    for (int i = 0; i < 4; i++) {
      int r = w * 32 + i * 8 + (lane >> 3);             // K row 0..127
      int c = (lane & 7) ^ (r & 7);
      gl_lds16(kbase + (size_t)(kt * 128 + r) * HD + c * 8, Ks + (w * 32 + i * 8) * 64);
      int dv = w * 16 + i * 4 + (lane >> 4);            // V^T row (d) 0..63
      int cv = (lane & 15) ^ (dv & 15);
      gl_lds16(vbase + (size_t)dv * SEQ + kt * 128 + cv * 8, Vs + (w * 16 + i * 4) * 128);
    }
  };

  stage(0, 0);

  // preload this wave's 32 q rows (B-frag layout: col = l15, k = quad*8+j)
  bf16x8 qf[2][2];
#pragma unroll
  for (int m = 0; m < 2; m++)
#pragma unroll
    for (int t = 0; t < 2; t++)
      qf[m][t] = *(const bf16x8*)(qbase + (size_t)(qt * 128 + w * 32 + m * 16 + l15) * HD
                                  + t * 32 + quad * 8);

  // all-ones A-fragment for the row-sum MFMA
  bf16x8 ones;
#pragma unroll
  for (int i = 0; i < 8; i++) ones[i] = (bf16)1.0f;

  f32x4 lacc[2];
  f32x4 oacc[2][4];
#pragma unroll
  for (int m = 0; m < 2; m++) {
    lacc[m] = f32x4{0.f, 0.f, 0.f, 0.f};
#pragma unroll
    for (int i = 0; i < 4; i++) oacc[m][i] = f32x4{0.f, 0.f, 0.f, 0.f};
  }

  __syncthreads();

  for (int kt = 0; kt < SEQ / 128; kt++) {
    const int buf = kt & 1;
    if (kt + 1 < SEQ / 128) stage(kt + 1, buf ^ 1);   // prefetch next tile
    const bf16* Ks = (const bf16*)(smem + buf * 32768);
    const bf16* Vs = Ks + 8192;

    __builtin_amdgcn_s_setprio(1);
#pragma unroll
    for (int t2 = 0; t2 < 4; t2++) {
      // S^T for k-block t2*32..t2*32+31: lane holds P[k=mk*16+quad*4+r][q=l15]
      bf16x8 pa[2];
#pragma unroll
      for (int hh = 0; hh < 2; hh++) {
        const int krow = (t2 * 2 + hh) * 16 + l15;     // A-frag: row = l15
        const int swz = krow & 7;
        bf16x8 kf0 = *(const bf16x8*)(Ks + krow * 64 + ((quad ^ swz) & 7) * 8);
        bf16x8 kf1 = *(const bf16x8*)(Ks + krow * 64 + (((4 + quad) ^ swz) & 7) * 8);
#pragma unroll
        for (int mq = 0; mq < 2; mq++) {
          f32x4 s = f32x4{0.f, 0.f, 0.f, 0.f};
          s = mfma16(kf0, qf[mq][0], s);
          s = mfma16(kf1, qf[mq][1], s);
#pragma unroll
          for (int r = 0; r < 4; r++)
            pa[mq][hh * 4 + r] = (bf16)__builtin_amdgcn_exp2f(s[r]);
        }
      }
      // PV: V pre-permuted so the b128 at chunk (t2*4+quad)^l15 holds exactly
      // k = t2*32 + (j>>2)*16 + quad*4 + (j&3) at slot j — matching pa.
#pragma unroll
      for (int dt = 0; dt < 4; dt++) {
        const int d = dt * 16 + l15;
        bf16x8 vv = *(const bf16x8*)(Vs + d * 128 + ((t2 * 4 + quad) ^ l15) * 8);
#pragma unroll
        for (int mq = 0; mq < 2; mq++)
          oacc[mq][dt] = mfma16(vv, pa[mq], oacc[mq][dt]);
      }
      // row-sum on the MFMA pipe: every output row = sum_k pa[k][q=l15]
#pragma unroll
      for (int mq = 0; mq < 2; mq++)
        lacc[mq] = mfma16(ones, pa[mq], lacc[mq]);
    }
    __builtin_amdgcn_s_setprio(0);
    __syncthreads();   // one barrier/kt: prefetch landed + buf free to overwrite
  }

  // rls straight from lacc (all 4 rows identical; no cross-lane reduce needed)
  float rls[2];
#pragma unroll
  for (int mq = 0; mq < 2; mq++)
    rls[mq] = __builtin_amdgcn_rcpf(lacc[mq][0]);

  // O^T blocks: oacc[mq][dt][r] = O[q = mq*16+l15][d = dt*16+quad*4+r]
  const int b = bh >> 4, h = bh & 15;
#pragma unroll
  for (int mq = 0; mq < 2; mq++) {
    const int srow = qt * 128 + w * 32 + mq * 16 + l15;
    bf16* orow = O + ((size_t)(b * SEQ + srow)) * EMB + h * HD;
#pragma unroll
    for (int dt = 0; dt < 4; dt++) {
      bf16x4 ov;
#pragma unroll
      for (int r = 0; r < 4; r++) ov[r] = (bf16)(oacc[mq][dt][r] * rls[mq]);
      *(bf16x4*)(orow + dt * 16 + quad * 4) = ov;      // packed 8B store
    }
  }
}

extern "C" void kernel_launch(void* const* d_in, const int* in_sizes, int n_in,
                              void* d_out, int out_size, void* d_ws, size_t ws_size,
                              hipStream_t stream) {
  const float* x  = (const float*)d_in[0];
  const float* Wq = (const float*)d_in[1];
  const float* bq = (const float*)d_in[2];
  const float* Wk = (const float*)d_in[3];
  const float* bk = (const float*)d_in[4];
  const float* Wv = (const float*)d_in[5];
  const float* bv = (const float*)d_in[6];
  const float* Wo = (const float*)d_in[7];
  const float* bo = (const float*)d_in[8];

  const size_t XN = (size_t)MTOT * EMB;  // 4,194,304
  const size_t WN = (size_t)EMB * EMB;   // 1,048,576

  bf16* xb = (bf16*)d_ws;                // [xb | wq | wk | wv | wo] contiguous
  bf16* wq = xb + XN;
  bf16* wk = wq + WN;
  bf16* wv = wk + WN;
  bf16* wo = wv + WN;
  bf16* q  = wo + WN;
  bf16* k  = q + XN;
  bf16* vt = k + XN;
  bf16* at = vt + XN;
  float* out = (float*)d_out;

  dim3 blk(256);
  cvt_all_kernel<<<dim3(512, 8), blk, 0, stream>>>(x, Wq, Wk, Wv, Wo, xb);

  gemm_kernel<<<dim3(16, 32, 3), blk, 0, stream>>>(
      xb, wq, wk, wv, bq, bk, bv, q, k, vt);
  flash_kernel<<<dim3(16, 32), blk, 0, stream>>>(q, k, vt, at);
  gemm_o_kernel<<<dim3(8, 64), blk, 0, stream>>>(at, wo, bo, out);
}

// Round 11
// 178.409 us; speedup vs baseline: 1.1418x; 1.0045x over previous
//
#include <hip/hip_runtime.h>
#include <hip/hip_bf16.h>
#include <math.h>

typedef __bf16 bf16;
typedef __bf16 bf16x4 __attribute__((ext_vector_type(4)));
typedef __bf16 bf16x8 __attribute__((ext_vector_type(8)));
typedef float f32x4 __attribute__((ext_vector_type(4)));

#define SEQ  2048
#define EMB  1024
#define NH   16
#define HD   64
#define MTOT 4096  // B*S

__device__ __forceinline__ void gl_lds16(const void* g, void* l) {
  __builtin_amdgcn_global_load_lds(
      (const __attribute__((address_space(1))) void*)g,
      (__attribute__((address_space(3))) void*)l, 16, 0, 0);
}

__device__ __forceinline__ f32x4 mfma16(bf16x8 a, bf16x8 b, f32x4 c) {
  return __builtin_amdgcn_mfma_f32_16x16x32_bf16(a, b, c, 0, 0, 0);
}

// log2(10000)/32
#define ROPE_C 0.41524101186092026f
// log2(e)/8 — QK scale, pre-folded into q at the projection epilogue
#define QSCL  0.1803368801111244f

// f32 -> bf16: 8 uniform WN-sized slices; y 0..3 = x chunks, y 4..7 = Wq..Wo.
__global__ __launch_bounds__(256) void cvt_all_kernel(
    const float* __restrict__ x,
    const float* __restrict__ w0, const float* __restrict__ w1,
    const float* __restrict__ w2, const float* __restrict__ w3,
    bf16* __restrict__ dst) {
  const int y = blockIdx.y;
  const size_t WN = (size_t)EMB * EMB;
  const float* src = (y < 4) ? (x + (size_t)y * WN)
                   : (y == 4) ? w0 : (y == 5) ? w1 : (y == 6) ? w2 : w3;
  size_t i = ((size_t)blockIdx.x * 256 + threadIdx.x) * 8;
  float4 a = *(const float4*)(src + i);
  float4 b = *(const float4*)(src + i + 4);
  bf16x8 o;
  o[0] = (bf16)a.x; o[1] = (bf16)a.y; o[2] = (bf16)a.z; o[3] = (bf16)a.w;
  o[4] = (bf16)b.x; o[5] = (bf16)b.y; o[6] = (bf16)b.z; o[7] = (bf16)b.w;
  *(bf16x8*)(dst + (size_t)y * WN + i) = o;
}

// QKV projection v3 (unfused z, 128m x 64n tile, BK=64): 1536 blocks ->
// ~6 blocks/CU — the grid, not resources, was capping occupancy; more
// independent blocks per CU overlap the per-block vmcnt(0) barrier drains
// (the m97-structure stall). LDS 24.6 KB/block, acc 4x2. Both-sides XOR
// swizzle (rule 21). Epilogues: 128x64 single-head (q/k: stride-72 CS +
// RoPE; v: stride-132 CS + 32-s block permute for flash's single-b128 PV
// fragment). q pre-scaled by QSCL. (R10-verified: total 190.7 -> 179.2.)
__global__ __launch_bounds__(256) void gemm_kernel(
    const bf16* __restrict__ X,
    const bf16* __restrict__ W0, const bf16* __restrict__ W1, const bf16* __restrict__ W2,
    const float* __restrict__ B0, const float* __restrict__ B1, const float* __restrict__ B2,
    bf16* __restrict__ Oq, bf16* __restrict__ Ok, bf16* __restrict__ Ovt)
{
  const int K = EMB;
  const int tid  = threadIdx.x;
  const int lane = tid & 63;
  const int w    = tid >> 6;       // wave 0..3
  const int wm   = w >> 1, wn = w & 1;
  // XCD swizzle within each z-slice: 64-block chunks per XCD. 512 = 8 * 64.
  const int lin = blockIdx.x + blockIdx.y * 16;
  const int sw  = (lin & 7) * 64 + (lin >> 3);
  const int tile_n = (sw & 15) * 64;     // 0..960
  const int tile_m = (sw >> 4) * 128;    // 0..3968
  const int z = blockIdx.z;
  const bf16*  Wsel = (z == 0) ? W0 : (z == 1 ? W1 : W2);
  const float* Bsel = (z == 0) ? B0 : (z == 1 ? B1 : B2);

  __shared__ __align__(16) unsigned char smem[24576];
  bf16* As = (bf16*)smem;            // 128 x 64 = 16 KB
  bf16* Bs = (bf16*)(smem + 16384);  //  64 x 64 =  8 KB

  f32x4 acc[4][2];
#pragma unroll
  for (int i = 0; i < 4; i++)
#pragma unroll
    for (int j = 0; j < 2; j++) acc[i][j] = f32x4{0.f, 0.f, 0.f, 0.f};

  const int quad  = lane >> 4;
  const int l15   = lane & 15;
  const int srow8 = lane >> 3;   // row within an 8-row staging issue
  const int p8    = lane & 7;    // 16B-chunk slot within the 128B row
  const int csrc  = p8 ^ srow8;  // global chunk feeding this LDS slot

  for (int k0 = 0; k0 < K; k0 += 64) {
#pragma unroll
    for (int i = 0; i < 4; i++) {
      const int ii = w * 4 + i;            // 8-row group 0..15
      const int r  = ii * 8 + srow8;       // A row 0..127
      gl_lds16(X + (size_t)(tile_m + r) * K + k0 + csrc * 8, As + ii * 512);
    }
#pragma unroll
    for (int i = 0; i < 2; i++) {
      const int ii = w * 2 + i;            // 8-row group 0..7
      const int r  = ii * 8 + srow8;       // B row 0..63
      gl_lds16(Wsel + (size_t)(tile_n + r) * K + k0 + csrc * 8, Bs + ii * 512);
    }
    __syncthreads();

#pragma unroll
    for (int kk = 0; kk < 2; kk++) {
      bf16x8 af[4], bfr[2];
#pragma unroll
      for (int mt = 0; mt < 4; mt++) {
        int ml = wm * 64 + mt * 16 + l15;
        af[mt] = *(const bf16x8*)(As + ml * 64 + (((kk * 4 + quad) ^ (ml & 7)) & 7) * 8);
      }
#pragma unroll
      for (int nt = 0; nt < 2; nt++) {
        int nl = wn * 32 + nt * 16 + l15;
        bfr[nt] = *(const bf16x8*)(Bs + nl * 64 + (((kk * 4 + quad) ^ (nl & 7)) & 7) * 8);
      }
#pragma unroll
      for (int mt = 0; mt < 4; mt++)
#pragma unroll
        for (int nt = 0; nt < 2; nt++)
          acc[mt][nt] = mfma16(af[mt], bfr[nt], acc[mt][nt]);
    }
    __syncthreads();
  }

  // ---- epilogue (128x64 single-head) ----
  bf16* CS = (bf16*)smem;
  const int b  = tile_m >> 11;
  const int s0 = tile_m & (SEQ - 1);
  const int hg = tile_n >> 6;          // tile spans exactly one head

  if (z < 2) {
    // bias + RoPE in registers, stage CS[m][n] stride 72
#pragma unroll
    for (int nt = 0; nt < 2; nt++) {
      const int nl = wn * 32 + nt * 16 + l15;
      const int n = tile_n + nl;
      const float bias = Bsel[n];
      const int j = n & 31;
      const float invf = exp2f(-(float)j * ROPE_C);
#pragma unroll
      for (int mt = 0; mt < 4; mt++) {
#pragma unroll
        for (int r = 0; r < 4; r++) {
          const int ml = wm * 64 + mt * 16 + quad * 4 + r;
          float a = acc[mt][nt][r] + bias;
          float p = __shfl_xor(a, 1, 64);  // partner at d^1 (incl. its bias)
          float th = (float)(s0 + ml) * invf;
          float sn, cs;
          __sincosf(th, &sn, &cs);
          float res = (n & 1) ? fmaf(p, sn, a * cs) : fmaf(-p, sn, a * cs);
          if (z == 0) res *= QSCL;  // fold QK scale+log2e into q
          CS[ml * 72 + nl] = (bf16)res;
        }
      }
    }
    __syncthreads();
    // coalesced copy: 128 rows x 64 cols (one head)
    bf16* Odst = (z == 0) ? Oq : Ok;
#pragma unroll
    for (int g = 0; g < 4; g++) {
      int unit = g * 256 + tid;
      int chunk = unit & 7;          // 16B chunk within row
      int row = unit >> 3;           // 0..127
      bf16x8 v = *(const bf16x8*)(CS + row * 72 + chunk * 8);
      size_t o = ((size_t)(b * NH + hg) * SEQ + s0 + row) * HD + chunk * 8;
      *(bf16x8*)(Odst + o) = v;
    }
  } else {
    // V^T: stage CS[n][perm(m)] stride 132 — permute s within each 32-block
    // so flash's per-lane fragment is contiguous 16B.
#pragma unroll
    for (int nt = 0; nt < 2; nt++) {
      const int nl = wn * 32 + nt * 16 + l15;
      const float bias = Bsel[tile_n + nl];
#pragma unroll
      for (int mt = 0; mt < 4; mt++) {
        const int mb = wm * 64 + mt * 16 + quad * 4;
#pragma unroll
        for (int r = 0; r < 4; r++) {
          const int ml = mb + r;
          const int mp = (ml & ~31) | ((ml & 12) << 1) | ((ml & 16) >> 2) | (ml & 3);
          CS[nl * 132 + mp] = (bf16)(acc[mt][nt][r] + bias);
        }
      }
    }
    __syncthreads();
    // coalesced copy: 64 rows (d) x 256 B
#pragma unroll
    for (int g = 0; g < 4; g++) {
      int unit = g * 256 + tid;
      int chunk = unit & 15;         // 16B chunk within row
      int row = unit >> 4;           // 0..63 (= d, tile spans one head)
      bf16x8 v = *(const bf16x8*)(CS + row * 132 + chunk * 8);
      size_t o = ((size_t)(b * NH + hg) * HD + row) * SEQ + s0 + chunk * 8;
      *(bf16x8*)(Ovt + o) = v;
    }
  }
}

// Out projection v3 = the R10-winning gemm-v3 main loop applied to Wo:
// 128m x 64n tile, BK=64, LDS 24.6 KB (As 16 + Bs 8) -> ~5-6 blocks/CU
// (was 48 KB -> 3). Same both-sides XOR swizzle and staging split. Epilogue:
// direct f32 stores with bias — each (mt,nt,r) writes 16 consecutive f32
// (64 B) per 16-lane group; keeps LDS at 24.6 KB so occupancy stays up.
__global__ __launch_bounds__(256) void gemm_o_kernel(
    const bf16* __restrict__ X,     // attn out [4096][1024] bf16
    const bf16* __restrict__ W,     // Wo [1024][1024] bf16
    const float* __restrict__ Bb,   // bo
    float* __restrict__ Out)        // [4096][1024] f32
{
  const int tid  = threadIdx.x;
  const int lane = tid & 63;
  const int w    = tid >> 6;       // wave 0..3
  const int wm   = w >> 1, wn = w & 1;
  // XCD swizzle: 64-block chunks per XCD. 512 = 8 * 64.
  const int lin = blockIdx.x + blockIdx.y * 16;
  const int sw  = (lin & 7) * 64 + (lin >> 3);
  const int tile_n = (sw & 15) * 64;     // 0..960
  const int tile_m = (sw >> 4) * 128;    // 0..3968

  __shared__ __align__(16) unsigned char smem[24576];
  bf16* As = (bf16*)smem;            // 128 x 64 = 16 KB
  bf16* Bs = (bf16*)(smem + 16384);  //  64 x 64 =  8 KB

  f32x4 acc[4][2];
#pragma unroll
  for (int i = 0; i < 4; i++)
#pragma unroll
    for (int j = 0; j < 2; j++) acc[i][j] = f32x4{0.f, 0.f, 0.f, 0.f};

  const int quad  = lane >> 4;
  const int l15   = lane & 15;
  const int srow8 = lane >> 3;
  const int p8    = lane & 7;
  const int csrc  = p8 ^ srow8;

  for (int k0 = 0; k0 < EMB; k0 += 64) {
#pragma unroll
    for (int i = 0; i < 4; i++) {
      const int ii = w * 4 + i;            // 8-row group 0..15
      const int r  = ii * 8 + srow8;       // A row 0..127
      gl_lds16(X + (size_t)(tile_m + r) * EMB + k0 + csrc * 8, As + ii * 512);
    }
#pragma unroll
    for (int i = 0; i < 2; i++) {
      const int ii = w * 2 + i;            // 8-row group 0..7
      const int r  = ii * 8 + srow8;       // B row 0..63
      gl_lds16(W + (size_t)(tile_n + r) * EMB + k0 + csrc * 8, Bs + ii * 512);
    }
    __syncthreads();

#pragma unroll
    for (int kk = 0; kk < 2; kk++) {
      bf16x8 af[4], bfr[2];
#pragma unroll
      for (int mt = 0; mt < 4; mt++) {
        int ml = wm * 64 + mt * 16 + l15;
        af[mt] = *(const bf16x8*)(As + ml * 64 + (((kk * 4 + quad) ^ (ml & 7)) & 7) * 8);
      }
#pragma unroll
      for (int nt = 0; nt < 2; nt++) {
        int nl = wn * 32 + nt * 16 + l15;
        bfr[nt] = *(const bf16x8*)(Bs + nl * 64 + (((kk * 4 + quad) ^ (nl & 7)) & 7) * 8);
      }
#pragma unroll
      for (int mt = 0; mt < 4; mt++)
#pragma unroll
        for (int nt = 0; nt < 2; nt++)
          acc[mt][nt] = mfma16(af[mt], bfr[nt], acc[mt][nt]);
    }
    __syncthreads();
  }

  // ---- epilogue: bias + direct f32 stores (64B per 16-lane group) ----
#pragma unroll
  for (int nt = 0; nt < 2; nt++) {
    const int n = tile_n + wn * 32 + nt * 16 + l15;
    const float bias = Bb[n];
#pragma unroll
    for (int mt = 0; mt < 4; mt++) {
#pragma unroll
      for (int r = 0; r < 4; r++) {
        const int m = tile_m + wm * 64 + mt * 16 + quad * 4 + r;
        Out[(size_t)m * EMB + n] = acc[mt][nt][r] + bias;
      }
    }
  }
}

// Flash attention v12 (R7/R10-verified best): LDS double-buffered K/V
// (KVBLK=128) via global_load_lds, 1 barrier/kt, swapped-QK^T lane-local P,
// pre-permuted V single-b128 PV (zero conflicts), XCD swizzle, setprio,
// ones-MFMA row-sum (denominator uses the same bf16-rounded P as the
// numerator).
__global__ __launch_bounds__(256) void flash_kernel(
    const bf16* __restrict__ Q,   // [bh][s][d], pre-scaled by log2(e)/8
    const bf16* __restrict__ Kk,  // [bh][s][d]
    const bf16* __restrict__ Vt,  // [bh][d][s], 32-s blocks permuted
    bf16* __restrict__ O)         // [b*S + s][h*64 + d]
{
  const int lin = blockIdx.x + blockIdx.y * 16;   // dispatch-linear, x fastest
  const int sw  = (lin & 7) * 64 + (lin >> 3);    // 8 XCDs x 64-block chunks
  const int bh  = sw >> 4;                        // 4 heads per XCD chunk
  const int qt  = sw & 15;                        // 128-row q tile
  const int tid = threadIdx.x, lane = tid & 63, w = tid >> 6;
  const int quad = lane >> 4, l15 = lane & 15;

  __shared__ __align__(16) unsigned char smem[65536];
  // buf b at smem + b*32768: [Ks 16KB: 128 krow x 64 d, chunk8^(row&7)]
  //                          [Vs 16KB:  64 d x 128 s,  chunk16^(d&15)]

  const bf16* qbase = Q  + (size_t)bh * SEQ * HD;
  const bf16* kbase = Kk + (size_t)bh * SEQ * HD;
  const bf16* vbase = Vt + (size_t)bh * HD * SEQ;

  // stage one K/V tile into buffer `buf` (zero-conflict pattern)
  auto stage = [&](int kt, int buf) {
    bf16* Ks = (bf16*)(smem + buf * 32768);
    bf16* Vs = Ks + 8192;
#pragma unroll
    for (int i = 0; i < 4; i++) {
      int r = w * 32 + i * 8 + (lane >> 3);             // K row 0..127
      int c = (lane & 7) ^ (r & 7);
      gl_lds16(kbase + (size_t)(kt * 128 + r) * HD + c * 8, Ks + (w * 32 + i * 8) * 64);
      int dv = w * 16 + i * 4 + (lane >> 4);            // V^T row (d) 0..63
      int cv = (lane & 15) ^ (dv & 15);
      gl_lds16(vbase + (size_t)dv * SEQ + kt * 128 + cv * 8, Vs + (w * 16 + i * 4) * 128);
    }
  };

  stage(0, 0);

  // preload this wave's 32 q rows (B-frag layout: col = l15, k = quad*8+j)
  bf16x8 qf[2][2];
#pragma unroll
  for (int m = 0; m < 2; m++)
#pragma unroll
    for (int t = 0; t < 2; t++)
      qf[m][t] = *(const bf16x8*)(qbase + (size_t)(qt * 128 + w * 32 + m * 16 + l15) * HD
                                  + t * 32 + quad * 8);

  // all-ones A-fragment for the row-sum MFMA
  bf16x8 ones;
#pragma unroll
  for (int i = 0; i < 8; i++) ones[i] = (bf16)1.0f;

  f32x4 lacc[2];
  f32x4 oacc[2][4];
#pragma unroll
  for (int m = 0; m < 2; m++) {
    lacc[m] = f32x4{0.f, 0.f, 0.f, 0.f};
#pragma unroll
    for (int i = 0; i < 4; i++) oacc[m][i] = f32x4{0.f, 0.f, 0.f, 0.f};
  }

  __syncthreads();

  for (int kt = 0; kt < SEQ / 128; kt++) {
    const int buf = kt & 1;
    if (kt + 1 < SEQ / 128) stage(kt + 1, buf ^ 1);   // prefetch next tile
    const bf16* Ks = (const bf16*)(smem + buf * 32768);
    const bf16* Vs = Ks + 8192;

    __builtin_amdgcn_s_setprio(1);
#pragma unroll
    for (int t2 = 0; t2 < 4; t2++) {
      // S^T for k-block t2*32..t2*32+31: lane holds P[k=mk*16+quad*4+r][q=l15]
      bf16x8 pa[2];
#pragma unroll
      for (int hh = 0; hh < 2; hh++) {
        const int krow = (t2 * 2 + hh) * 16 + l15;     // A-frag: row = l15
        const int swz = krow & 7;
        bf16x8 kf0 = *(const bf16x8*)(Ks + krow * 64 + ((quad ^ swz) & 7) * 8);
        bf16x8 kf1 = *(const bf16x8*)(Ks + krow * 64 + (((4 + quad) ^ swz) & 7) * 8);
#pragma unroll
        for (int mq = 0; mq < 2; mq++) {
          f32x4 s = f32x4{0.f, 0.f, 0.f, 0.f};
          s = mfma16(kf0, qf[mq][0], s);
          s = mfma16(kf1, qf[mq][1], s);
#pragma unroll
          for (int r = 0; r < 4; r++)
            pa[mq][hh * 4 + r] = (bf16)__builtin_amdgcn_exp2f(s[r]);
        }
      }
      // PV: V pre-permuted so the b128 at chunk (t2*4+quad)^l15 holds exactly
      // k = t2*32 + (j>>2)*16 + quad*4 + (j&3) at slot j — matching pa.
#pragma unroll
      for (int dt = 0; dt < 4; dt++) {
        const int d = dt * 16 + l15;
        bf16x8 vv = *(const bf16x8*)(Vs + d * 128 + ((t2 * 4 + quad) ^ l15) * 8);
#pragma unroll
        for (int mq = 0; mq < 2; mq++)
          oacc[mq][dt] = mfma16(vv, pa[mq], oacc[mq][dt]);
      }
      // row-sum on the MFMA pipe: every output row = sum_k pa[k][q=l15]
#pragma unroll
      for (int mq = 0; mq < 2; mq++)
        lacc[mq] = mfma16(ones, pa[mq], lacc[mq]);
    }
    __builtin_amdgcn_s_setprio(0);
    __syncthreads();   // one barrier/kt: prefetch landed + buf free to overwrite
  }

  // rls straight from lacc (all 4 rows identical; no cross-lane reduce needed)
  float rls[2];
#pragma unroll
  for (int mq = 0; mq < 2; mq++)
    rls[mq] = __builtin_amdgcn_rcpf(lacc[mq][0]);

  // O^T blocks: oacc[mq][dt][r] = O[q = mq*16+l15][d = dt*16+quad*4+r]
  const int b = bh >> 4, h = bh & 15;
#pragma unroll
  for (int mq = 0; mq < 2; mq++) {
    const int srow = qt * 128 + w * 32 + mq * 16 + l15;
    bf16* orow = O + ((size_t)(b * SEQ + srow)) * EMB + h * HD;
#pragma unroll
    for (int dt = 0; dt < 4; dt++) {
      bf16x4 ov;
#pragma unroll
      for (int r = 0; r < 4; r++) ov[r] = (bf16)(oacc[mq][dt][r] * rls[mq]);
      *(bf16x4*)(orow + dt * 16 + quad * 4) = ov;      // packed 8B store
    }
  }
}

extern "C" void kernel_launch(void* const* d_in, const int* in_sizes, int n_in,
                              void* d_out, int out_size, void* d_ws, size_t ws_size,
                              hipStream_t stream) {
  const float* x  = (const float*)d_in[0];
  const float* Wq = (const float*)d_in[1];
  const float* bq = (const float*)d_in[2];
  const float* Wk = (const float*)d_in[3];
  const float* bk = (const float*)d_in[4];
  const float* Wv = (const float*)d_in[5];
  const float* bv = (const float*)d_in[6];
  const float* Wo = (const float*)d_in[7];
  const float* bo = (const float*)d_in[8];

  const size_t XN = (size_t)MTOT * EMB;  // 4,194,304
  const size_t WN = (size_t)EMB * EMB;   // 1,048,576

  bf16* xb = (bf16*)d_ws;                // [xb | wq | wk | wv | wo] contiguous
  bf16* wq = xb + XN;
  bf16* wk = wq + WN;
  bf16* wv = wk + WN;
  bf16* wo = wv + WN;
  bf16* q  = wo + WN;
  bf16* k  = q + XN;
  bf16* vt = k + XN;
  bf16* at = vt + XN;
  float* out = (float*)d_out;

  dim3 blk(256);
  cvt_all_kernel<<<dim3(512, 8), blk, 0, stream>>>(x, Wq, Wk, Wv, Wo, xb);

  gemm_kernel<<<dim3(16, 32, 3), blk, 0, stream>>>(
      xb, wq, wk, wv, bq, bk, bv, q, k, vt);
  flash_kernel<<<dim3(16, 32), blk, 0, stream>>>(q, k, vt, at);
  gemm_o_kernel<<<dim3(16, 32), blk, 0, stream>>>(at, wo, bo, out);
}

// Round 12
// 174.663 us; speedup vs baseline: 1.1663x; 1.0215x over previous
//
#include <hip/hip_runtime.h>
#include <hip/hip_bf16.h>
#include <math.h>

typedef __bf16 bf16;
typedef __bf16 bf16x4 __attribute__((ext_vector_type(4)));
typedef __bf16 bf16x8 __attribute__((ext_vector_type(8)));
typedef float f32x4 __attribute__((ext_vector_type(4)));

#define SEQ  2048
#define EMB  1024
#define NH   16
#define HD   64
#define MTOT 4096  // B*S

__device__ __forceinline__ void gl_lds16(const void* g, void* l) {
  __builtin_amdgcn_global_load_lds(
      (const __attribute__((address_space(1))) void*)g,
      (__attribute__((address_space(3))) void*)l, 16, 0, 0);
}

__device__ __forceinline__ f32x4 mfma16(bf16x8 a, bf16x8 b, f32x4 c) {
  return __builtin_amdgcn_mfma_f32_16x16x32_bf16(a, b, c, 0, 0, 0);
}

// log2(10000)/32
#define ROPE_C 0.41524101186092026f
// log2(e)/8 — QK scale, pre-folded into q at the projection epilogue
#define QSCL  0.1803368801111244f

// f32 -> bf16: 8 uniform WN-sized slices; y 0..3 = x chunks, y 4..7 = Wq..Wo.
__global__ __launch_bounds__(256) void cvt_all_kernel(
    const float* __restrict__ x,
    const float* __restrict__ w0, const float* __restrict__ w1,
    const float* __restrict__ w2, const float* __restrict__ w3,
    bf16* __restrict__ dst) {
  const int y = blockIdx.y;
  const size_t WN = (size_t)EMB * EMB;
  const float* src = (y < 4) ? (x + (size_t)y * WN)
                   : (y == 4) ? w0 : (y == 5) ? w1 : (y == 6) ? w2 : w3;
  size_t i = ((size_t)blockIdx.x * 256 + threadIdx.x) * 8;
  float4 a = *(const float4*)(src + i);
  float4 b = *(const float4*)(src + i + 4);
  bf16x8 o;
  o[0] = (bf16)a.x; o[1] = (bf16)a.y; o[2] = (bf16)a.z; o[3] = (bf16)a.w;
  o[4] = (bf16)b.x; o[5] = (bf16)b.y; o[6] = (bf16)b.z; o[7] = (bf16)b.w;
  *(bf16x8*)(dst + (size_t)y * WN + i) = o;
}

// QKV projection v3 (unfused z, 128m x 64n tile, BK=64): 1536 blocks ->
// ~6 blocks/CU — the grid, not resources, was capping occupancy; more
// independent blocks per CU overlap the per-block vmcnt(0) barrier drains
// (the m97-structure stall). LDS 24.6 KB/block, acc 4x2. Both-sides XOR
// swizzle (rule 21). Epilogues: 128x64 single-head (q/k: stride-72 CS +
// RoPE; v: stride-132 CS + 32-s block permute for flash's single-b128 PV
// fragment). q pre-scaled by QSCL. (R10-verified: total 190.7 -> 179.2.)
__global__ __launch_bounds__(256) void gemm_kernel(
    const bf16* __restrict__ X,
    const bf16* __restrict__ W0, const bf16* __restrict__ W1, const bf16* __restrict__ W2,
    const float* __restrict__ B0, const float* __restrict__ B1, const float* __restrict__ B2,
    bf16* __restrict__ Oq, bf16* __restrict__ Ok, bf16* __restrict__ Ovt)
{
  const int K = EMB;
  const int tid  = threadIdx.x;
  const int lane = tid & 63;
  const int w    = tid >> 6;       // wave 0..3
  const int wm   = w >> 1, wn = w & 1;
  // XCD swizzle within each z-slice: 64-block chunks per XCD. 512 = 8 * 64.
  const int lin = blockIdx.x + blockIdx.y * 16;
  const int sw  = (lin & 7) * 64 + (lin >> 3);
  const int tile_n = (sw & 15) * 64;     // 0..960
  const int tile_m = (sw >> 4) * 128;    // 0..3968
  const int z = blockIdx.z;
  const bf16*  Wsel = (z == 0) ? W0 : (z == 1 ? W1 : W2);
  const float* Bsel = (z == 0) ? B0 : (z == 1 ? B1 : B2);

  __shared__ __align__(16) unsigned char smem[24576];
  bf16* As = (bf16*)smem;            // 128 x 64 = 16 KB
  bf16* Bs = (bf16*)(smem + 16384);  //  64 x 64 =  8 KB

  f32x4 acc[4][2];
#pragma unroll
  for (int i = 0; i < 4; i++)
#pragma unroll
    for (int j = 0; j < 2; j++) acc[i][j] = f32x4{0.f, 0.f, 0.f, 0.f};

  const int quad  = lane >> 4;
  const int l15   = lane & 15;
  const int srow8 = lane >> 3;   // row within an 8-row staging issue
  const int p8    = lane & 7;    // 16B-chunk slot within the 128B row
  const int csrc  = p8 ^ srow8;  // global chunk feeding this LDS slot

  for (int k0 = 0; k0 < K; k0 += 64) {
#pragma unroll
    for (int i = 0; i < 4; i++) {
      const int ii = w * 4 + i;            // 8-row group 0..15
      const int r  = ii * 8 + srow8;       // A row 0..127
      gl_lds16(X + (size_t)(tile_m + r) * K + k0 + csrc * 8, As + ii * 512);
    }
#pragma unroll
    for (int i = 0; i < 2; i++) {
      const int ii = w * 2 + i;            // 8-row group 0..7
      const int r  = ii * 8 + srow8;       // B row 0..63
      gl_lds16(Wsel + (size_t)(tile_n + r) * K + k0 + csrc * 8, Bs + ii * 512);
    }
    __syncthreads();

#pragma unroll
    for (int kk = 0; kk < 2; kk++) {
      bf16x8 af[4], bfr[2];
#pragma unroll
      for (int mt = 0; mt < 4; mt++) {
        int ml = wm * 64 + mt * 16 + l15;
        af[mt] = *(const bf16x8*)(As + ml * 64 + (((kk * 4 + quad) ^ (ml & 7)) & 7) * 8);
      }
#pragma unroll
      for (int nt = 0; nt < 2; nt++) {
        int nl = wn * 32 + nt * 16 + l15;
        bfr[nt] = *(const bf16x8*)(Bs + nl * 64 + (((kk * 4 + quad) ^ (nl & 7)) & 7) * 8);
      }
#pragma unroll
      for (int mt = 0; mt < 4; mt++)
#pragma unroll
        for (int nt = 0; nt < 2; nt++)
          acc[mt][nt] = mfma16(af[mt], bfr[nt], acc[mt][nt]);
    }
    __syncthreads();
  }

  // ---- epilogue (128x64 single-head) ----
  bf16* CS = (bf16*)smem;
  const int b  = tile_m >> 11;
  const int s0 = tile_m & (SEQ - 1);
  const int hg = tile_n >> 6;          // tile spans exactly one head

  if (z < 2) {
    // bias + RoPE in registers, stage CS[m][n] stride 72
#pragma unroll
    for (int nt = 0; nt < 2; nt++) {
      const int nl = wn * 32 + nt * 16 + l15;
      const int n = tile_n + nl;
      const float bias = Bsel[n];
      const int j = n & 31;
      const float invf = exp2f(-(float)j * ROPE_C);
#pragma unroll
      for (int mt = 0; mt < 4; mt++) {
#pragma unroll
        for (int r = 0; r < 4; r++) {
          const int ml = wm * 64 + mt * 16 + quad * 4 + r;
          float a = acc[mt][nt][r] + bias;
          float p = __shfl_xor(a, 1, 64);  // partner at d^1 (incl. its bias)
          float th = (float)(s0 + ml) * invf;
          float sn, cs;
          __sincosf(th, &sn, &cs);
          float res = (n & 1) ? fmaf(p, sn, a * cs) : fmaf(-p, sn, a * cs);
          if (z == 0) res *= QSCL;  // fold QK scale+log2e into q
          CS[ml * 72 + nl] = (bf16)res;
        }
      }
    }
    __syncthreads();
    // coalesced copy: 128 rows x 64 cols (one head)
    bf16* Odst = (z == 0) ? Oq : Ok;
#pragma unroll
    for (int g = 0; g < 4; g++) {
      int unit = g * 256 + tid;
      int chunk = unit & 7;          // 16B chunk within row
      int row = unit >> 3;           // 0..127
      bf16x8 v = *(const bf16x8*)(CS + row * 72 + chunk * 8);
      size_t o = ((size_t)(b * NH + hg) * SEQ + s0 + row) * HD + chunk * 8;
      *(bf16x8*)(Odst + o) = v;
    }
  } else {
    // V^T: stage CS[n][perm(m)] stride 132 — permute s within each 32-block
    // so flash's per-lane fragment is contiguous 16B.
#pragma unroll
    for (int nt = 0; nt < 2; nt++) {
      const int nl = wn * 32 + nt * 16 + l15;
      const float bias = Bsel[tile_n + nl];
#pragma unroll
      for (int mt = 0; mt < 4; mt++) {
        const int mb = wm * 64 + mt * 16 + quad * 4;
#pragma unroll
        for (int r = 0; r < 4; r++) {
          const int ml = mb + r;
          const int mp = (ml & ~31) | ((ml & 12) << 1) | ((ml & 16) >> 2) | (ml & 3);
          CS[nl * 132 + mp] = (bf16)(acc[mt][nt][r] + bias);
        }
      }
    }
    __syncthreads();
    // coalesced copy: 64 rows (d) x 256 B
#pragma unroll
    for (int g = 0; g < 4; g++) {
      int unit = g * 256 + tid;
      int chunk = unit & 15;         // 16B chunk within row
      int row = unit >> 4;           // 0..63 (= d, tile spans one head)
      bf16x8 v = *(const bf16x8*)(CS + row * 132 + chunk * 8);
      size_t o = ((size_t)(b * NH + hg) * HD + row) * SEQ + s0 + chunk * 8;
      *(bf16x8*)(Ovt + o) = v;
    }
  }
}

// Out projection v3 = the R10-winning gemm-v3 main loop applied to Wo:
// 128m x 64n tile, BK=64, LDS 24.6 KB -> ~5-6 blocks/CU. Same both-sides
// XOR swizzle and staging split. Epilogue: direct f32 stores with bias.
__global__ __launch_bounds__(256) void gemm_o_kernel(
    const bf16* __restrict__ X,     // attn out [4096][1024] bf16
    const bf16* __restrict__ W,     // Wo [1024][1024] bf16
    const float* __restrict__ Bb,   // bo
    float* __restrict__ Out)        // [4096][1024] f32
{
  const int tid  = threadIdx.x;
  const int lane = tid & 63;
  const int w    = tid >> 6;       // wave 0..3
  const int wm   = w >> 1, wn = w & 1;
  // XCD swizzle: 64-block chunks per XCD. 512 = 8 * 64.
  const int lin = blockIdx.x + blockIdx.y * 16;
  const int sw  = (lin & 7) * 64 + (lin >> 3);
  const int tile_n = (sw & 15) * 64;     // 0..960
  const int tile_m = (sw >> 4) * 128;    // 0..3968

  __shared__ __align__(16) unsigned char smem[24576];
  bf16* As = (bf16*)smem;            // 128 x 64 = 16 KB
  bf16* Bs = (bf16*)(smem + 16384);  //  64 x 64 =  8 KB

  f32x4 acc[4][2];
#pragma unroll
  for (int i = 0; i < 4; i++)
#pragma unroll
    for (int j = 0; j < 2; j++) acc[i][j] = f32x4{0.f, 0.f, 0.f, 0.f};

  const int quad  = lane >> 4;
  const int l15   = lane & 15;
  const int srow8 = lane >> 3;
  const int p8    = lane & 7;
  const int csrc  = p8 ^ srow8;

  for (int k0 = 0; k0 < EMB; k0 += 64) {
#pragma unroll
    for (int i = 0; i < 4; i++) {
      const int ii = w * 4 + i;            // 8-row group 0..15
      const int r  = ii * 8 + srow8;       // A row 0..127
      gl_lds16(X + (size_t)(tile_m + r) * EMB + k0 + csrc * 8, As + ii * 512);
    }
#pragma unroll
    for (int i = 0; i < 2; i++) {
      const int ii = w * 2 + i;            // 8-row group 0..7
      const int r  = ii * 8 + srow8;       // B row 0..63
      gl_lds16(W + (size_t)(tile_n + r) * EMB + k0 + csrc * 8, Bs + ii * 512);
    }
    __syncthreads();

#pragma unroll
    for (int kk = 0; kk < 2; kk++) {
      bf16x8 af[4], bfr[2];
#pragma unroll
      for (int mt = 0; mt < 4; mt++) {
        int ml = wm * 64 + mt * 16 + l15;
        af[mt] = *(const bf16x8*)(As + ml * 64 + (((kk * 4 + quad) ^ (ml & 7)) & 7) * 8);
      }
#pragma unroll
      for (int nt = 0; nt < 2; nt++) {
        int nl = wn * 32 + nt * 16 + l15;
        bfr[nt] = *(const bf16x8*)(Bs + nl * 64 + (((kk * 4 + quad) ^ (nl & 7)) & 7) * 8);
      }
#pragma unroll
      for (int mt = 0; mt < 4; mt++)
#pragma unroll
        for (int nt = 0; nt < 2; nt++)
          acc[mt][nt] = mfma16(af[mt], bfr[nt], acc[mt][nt]);
    }
    __syncthreads();
  }

  // ---- epilogue: bias + direct f32 stores (64B per 16-lane group) ----
#pragma unroll
  for (int nt = 0; nt < 2; nt++) {
    const int n = tile_n + wn * 32 + nt * 16 + l15;
    const float bias = Bb[n];
#pragma unroll
    for (int mt = 0; mt < 4; mt++) {
#pragma unroll
      for (int r = 0; r < 4; r++) {
        const int m = tile_m + wm * 64 + mt * 16 + quad * 4 + r;
        Out[(size_t)m * EMB + n] = acc[mt][nt][r] + bias;
      }
    }
  }
}

// Flash attention v14 = v12 per-wave structure at ONE 512-thread block per CU
// (256-q tile, 8 waves x 32 q): every per-wave quantity is byte-identical
// (fragments, LDS layout/swizzles, 88 VGPR, 2 waves/SIMD), but each K/V tile
// is staged ONCE per 256 q rows instead of twice (2x128-q blocks per CU) —
// halving gl_lds issues, LDS write-port pressure, and FETCH per unit work.
// Grid 256 = 1 block/CU; XCD swizzle 32-block chunks = 4 heads per XCD L2.
__global__ __launch_bounds__(512) void flash_kernel(
    const bf16* __restrict__ Q,   // [bh][s][d], pre-scaled by log2(e)/8
    const bf16* __restrict__ Kk,  // [bh][s][d]
    const bf16* __restrict__ Vt,  // [bh][d][s], 32-s blocks permuted
    bf16* __restrict__ O)         // [b*S + s][h*64 + d]
{
  const int lin = blockIdx.x + blockIdx.y * 8;    // grid (8,32) = 256 blocks
  const int sw  = (lin & 7) * 32 + (lin >> 3);    // 8 XCDs x 32-block chunks
  const int bh  = sw >> 3;                        // 4 heads per XCD chunk
  const int qt  = sw & 7;                         // 256-row q tile
  const int tid = threadIdx.x, lane = tid & 63, w = tid >> 6;  // w 0..7
  const int quad = lane >> 4, l15 = lane & 15;

  __shared__ __align__(16) unsigned char smem[65536];
  // buf b at smem + b*32768: [Ks 16KB: 128 krow x 64 d, chunk8^(row&7)]
  //                          [Vs 16KB:  64 d x 128 s,  chunk16^(d&15)]

  const bf16* qbase = Q  + (size_t)bh * SEQ * HD;
  const bf16* kbase = Kk + (size_t)bh * SEQ * HD;
  const bf16* vbase = Vt + (size_t)bh * HD * SEQ;

  // stage one K/V tile into buffer `buf` (zero-conflict pattern, 8 waves)
  auto stage = [&](int kt, int buf) {
    bf16* Ks = (bf16*)(smem + buf * 32768);
    bf16* Vs = Ks + 8192;
#pragma unroll
    for (int i = 0; i < 2; i++) {
      int r = w * 16 + i * 8 + (lane >> 3);             // K row 0..127
      int c = (lane & 7) ^ (r & 7);
      gl_lds16(kbase + (size_t)(kt * 128 + r) * HD + c * 8, Ks + (w * 16 + i * 8) * 64);
      int dv = w * 8 + i * 4 + (lane >> 4);             // V^T row (d) 0..63
      int cv = (lane & 15) ^ (dv & 15);
      gl_lds16(vbase + (size_t)dv * SEQ + kt * 128 + cv * 8, Vs + (w * 8 + i * 4) * 128);
    }
  };

  stage(0, 0);

  // preload this wave's 32 q rows (B-frag layout: col = l15, k = quad*8+j)
  bf16x8 qf[2][2];
#pragma unroll
  for (int m = 0; m < 2; m++)
#pragma unroll
    for (int t = 0; t < 2; t++)
      qf[m][t] = *(const bf16x8*)(qbase + (size_t)(qt * 256 + w * 32 + m * 16 + l15) * HD
                                  + t * 32 + quad * 8);

  // all-ones A-fragment for the row-sum MFMA
  bf16x8 ones;
#pragma unroll
  for (int i = 0; i < 8; i++) ones[i] = (bf16)1.0f;

  f32x4 lacc[2];
  f32x4 oacc[2][4];
#pragma unroll
  for (int m = 0; m < 2; m++) {
    lacc[m] = f32x4{0.f, 0.f, 0.f, 0.f};
#pragma unroll
    for (int i = 0; i < 4; i++) oacc[m][i] = f32x4{0.f, 0.f, 0.f, 0.f};
  }

  __syncthreads();

  for (int kt = 0; kt < SEQ / 128; kt++) {
    const int buf = kt & 1;
    if (kt + 1 < SEQ / 128) stage(kt + 1, buf ^ 1);   // prefetch next tile
    const bf16* Ks = (const bf16*)(smem + buf * 32768);
    const bf16* Vs = Ks + 8192;

    __builtin_amdgcn_s_setprio(1);
#pragma unroll
    for (int t2 = 0; t2 < 4; t2++) {
      // S^T for k-block t2*32..t2*32+31: lane holds P[k=mk*16+quad*4+r][q=l15]
      bf16x8 pa[2];
#pragma unroll
      for (int hh = 0; hh < 2; hh++) {
        const int krow = (t2 * 2 + hh) * 16 + l15;     // A-frag: row = l15
        const int swz = krow & 7;
        bf16x8 kf0 = *(const bf16x8*)(Ks + krow * 64 + ((quad ^ swz) & 7) * 8);
        bf16x8 kf1 = *(const bf16x8*)(Ks + krow * 64 + (((4 + quad) ^ swz) & 7) * 8);
#pragma unroll
        for (int mq = 0; mq < 2; mq++) {
          f32x4 s = f32x4{0.f, 0.f, 0.f, 0.f};
          s = mfma16(kf0, qf[mq][0], s);
          s = mfma16(kf1, qf[mq][1], s);
#pragma unroll
          for (int r = 0; r < 4; r++)
            pa[mq][hh * 4 + r] = (bf16)__builtin_amdgcn_exp2f(s[r]);
        }
      }
      // PV: V pre-permuted so the b128 at chunk (t2*4+quad)^l15 holds exactly
      // k = t2*32 + (j>>2)*16 + quad*4 + (j&3) at slot j — matching pa.
#pragma unroll
      for (int dt = 0; dt < 4; dt++) {
        const int d = dt * 16 + l15;
        bf16x8 vv = *(const bf16x8*)(Vs + d * 128 + ((t2 * 4 + quad) ^ l15) * 8);
#pragma unroll
        for (int mq = 0; mq < 2; mq++)
          oacc[mq][dt] = mfma16(vv, pa[mq], oacc[mq][dt]);
      }
      // row-sum on the MFMA pipe: every output row = sum_k pa[k][q=l15]
#pragma unroll
      for (int mq = 0; mq < 2; mq++)
        lacc[mq] = mfma16(ones, pa[mq], lacc[mq]);
    }
    __builtin_amdgcn_s_setprio(0);
    __syncthreads();   // one barrier/kt: prefetch landed + buf free to overwrite
  }

  // rls straight from lacc (all 4 rows identical; no cross-lane reduce needed)
  float rls[2];
#pragma unroll
  for (int mq = 0; mq < 2; mq++)
    rls[mq] = __builtin_amdgcn_rcpf(lacc[mq][0]);

  // O^T blocks: oacc[mq][dt][r] = O[q = mq*16+l15][d = dt*16+quad*4+r]
  const int b = bh >> 4, h = bh & 15;
#pragma unroll
  for (int mq = 0; mq < 2; mq++) {
    const int srow = qt * 256 + w * 32 + mq * 16 + l15;
    bf16* orow = O + ((size_t)(b * SEQ + srow)) * EMB + h * HD;
#pragma unroll
    for (int dt = 0; dt < 4; dt++) {
      bf16x4 ov;
#pragma unroll
      for (int r = 0; r < 4; r++) ov[r] = (bf16)(oacc[mq][dt][r] * rls[mq]);
      *(bf16x4*)(orow + dt * 16 + quad * 4) = ov;      // packed 8B store
    }
  }
}

extern "C" void kernel_launch(void* const* d_in, const int* in_sizes, int n_in,
                              void* d_out, int out_size, void* d_ws, size_t ws_size,
                              hipStream_t stream) {
  const float* x  = (const float*)d_in[0];
  const float* Wq = (const float*)d_in[1];
  const float* bq = (const float*)d_in[2];
  const float* Wk = (const float*)d_in[3];
  const float* bk = (const float*)d_in[4];
  const float* Wv = (const float*)d_in[5];
  const float* bv = (const float*)d_in[6];
  const float* Wo = (const float*)d_in[7];
  const float* bo = (const float*)d_in[8];

  const size_t XN = (size_t)MTOT * EMB;  // 4,194,304
  const size_t WN = (size_t)EMB * EMB;   // 1,048,576

  bf16* xb = (bf16*)d_ws;                // [xb | wq | wk | wv | wo] contiguous
  bf16* wq = xb + XN;
  bf16* wk = wq + WN;
  bf16* wv = wk + WN;
  bf16* wo = wv + WN;
  bf16* q  = wo + WN;
  bf16* k  = q + XN;
  bf16* vt = k + XN;
  bf16* at = vt + XN;
  float* out = (float*)d_out;

  dim3 blk(256);
  cvt_all_kernel<<<dim3(512, 8), blk, 0, stream>>>(x, Wq, Wk, Wv, Wo, xb);

  gemm_kernel<<<dim3(16, 32, 3), blk, 0, stream>>>(
      xb, wq, wk, wv, bq, bk, bv, q, k, vt);
  flash_kernel<<<dim3(8, 32), dim3(512), 0, stream>>>(q, k, vt, at);
  gemm_o_kernel<<<dim3(16, 32), blk, 0, stream>>>(at, wo, bo, out);
}